// Round 1
// baseline (1334.734 us; speedup 1.0000x reference)
//
#include <hip/hip_runtime.h>
#include <hip/hip_bf16.h>
#include <math.h>

#define B_      256
#define DA      1024
#define S_      8
#define DK      128
#define NKEYS   100000
#define KMAX    32

// ---------------------------------------------------------------------------
// Pass A: queries = einsum('ska,ba->bsk', W_Q, z), L2-normalized (fp64 acc).
// Output QT[s][k][b] fp32 (k-major x b for coalesced staging in pass B).
// ---------------------------------------------------------------------------
__global__ __launch_bounds__(128) void pass_a_kernel(
    const float* __restrict__ z, const float* __restrict__ wq,
    float* __restrict__ QT)
{
    const int b = blockIdx.x;
    const int s = blockIdx.y;
    __shared__ float zsh[DA];
    for (int i = threadIdx.x; i < DA; i += 128) zsh[i] = z[b * DA + i];
    __syncthreads();
    const int k = threadIdx.x;
    const float* wrow = wq + (size_t)(s * DK + k) * DA;
    double acc = 0.0;
    #pragma unroll 4
    for (int a = 0; a < DA; a += 4) {
        const float4 w4 = *reinterpret_cast<const float4*>(wrow + a);
        acc += (double)w4.x * (double)zsh[a + 0];
        acc += (double)w4.y * (double)zsh[a + 1];
        acc += (double)w4.z * (double)zsh[a + 2];
        acc += (double)w4.w * (double)zsh[a + 3];
    }
    double sq = acc * acc;
    #pragma unroll
    for (int off = 32; off > 0; off >>= 1) sq += __shfl_down(sq, off);
    __shared__ double part[2];
    if ((threadIdx.x & 63) == 0) part[threadIdx.x >> 6] = sq;
    __syncthreads();
    const double ss  = part[0] + part[1];
    const double inv = 1.0 / (sqrt(ss) + 1e-8);
    QT[(size_t)(s * DK + k) * B_ + b] = (float)(acc * inv);
}

// ---------------------------------------------------------------------------
// Pass K: F[s][n] = softmax(aspect_weights)[s] / (||pool_keys[s,n,:]|| + eps)
// 16 lanes per key row; fp64 sum of squares.
// ---------------------------------------------------------------------------
__global__ __launch_bounds__(256) void pass_k_kernel(
    const float* __restrict__ keys, const float* __restrict__ aw,
    float* __restrict__ F)
{
    float e[S_];
    float mx = aw[0];
    #pragma unroll
    for (int i = 1; i < S_; ++i) mx = fmaxf(mx, aw[i]);
    float se = 0.f;
    #pragma unroll
    for (int i = 0; i < S_; ++i) { e[i] = expf(aw[i] - mx); se += e[i]; }

    const int g = threadIdx.x >> 4, l = threadIdx.x & 15;
    const long long sn = (long long)blockIdx.x * 16 + g;   // S_*NKEYS = 800000 = 50000*16 exact
    const float* row = keys + (size_t)sn * DK + l * 8;
    const float4 r0 = *reinterpret_cast<const float4*>(row + 0);
    const float4 r1 = *reinterpret_cast<const float4*>(row + 4);
    double sq = (double)r0.x * r0.x + (double)r0.y * r0.y +
                (double)r0.z * r0.z + (double)r0.w * r0.w +
                (double)r1.x * r1.x + (double)r1.y * r1.y +
                (double)r1.z * r1.z + (double)r1.w * r1.w;
    #pragma unroll
    for (int off = 1; off < 16; off <<= 1) sq += __shfl_xor(sq, off);
    if (l == 0) {
        const int s = (int)(sn / NKEYS);
        const float w = e[s] / se;
        F[sn] = (float)((double)w / (sqrt(sq) + 1e-8));
    }
}

// ---------------------------------------------------------------------------
// Pass B: coarse scores s_i[b][n] = sum_{s,k} qn[b,s,k] * key[s,n,k]*F[s][n]
// fp32 FMA, 128x128 block tile, 8x8 micro-tile, keys pre-scaled in LDS.
// Output bf16 (coarse only -- exact values recomputed in pass C).
// ---------------------------------------------------------------------------
#define NT  128
#define BT  128
#define KC  32
#define LDP 132   // padded LDS row (float count), keeps 16B alignment

__global__ __launch_bounds__(256) void pass_b_kernel(
    const float* __restrict__ keys, const float* __restrict__ QT,
    const float* __restrict__ F, __hip_bfloat16* __restrict__ C)
{
    const int n0 = blockIdx.x * NT;
    const int b0 = blockIdx.y * BT;
    __shared__ float Ks[KC][LDP];
    __shared__ float Qs[KC][LDP];
    const int tid = threadIdx.x;
    const int tx = tid & 15;
    const int ty = tid >> 4;
    float acc[8][8] = {};

    for (int s = 0; s < S_; ++s) {
        const float* kbase = keys + (size_t)s * NKEYS * DK;
        const float* fbase = F + (size_t)s * NKEYS;
        for (int kc = 0; kc < DK; kc += KC) {
            __syncthreads();
            // stage Q chunk [KC][BT]
            for (int i = tid; i < KC * (BT / 4); i += 256) {
                const int kk = i / (BT / 4);
                const int bq = (i % (BT / 4)) * 4;
                const float4 v = *reinterpret_cast<const float4*>(
                    QT + (size_t)(s * DK + kc + kk) * B_ + b0 + bq);
                *reinterpret_cast<float4*>(&Qs[kk][bq]) = v;
            }
            // stage K chunk [KC][NT], scaled by F (folds w_s and key norm)
            for (int i = tid; i < NT * (KC / 4); i += 256) {
                const int nl = i >> 3;
                const int k4 = (i & 7) * 4;
                const int n  = n0 + nl;
                float4 v = make_float4(0.f, 0.f, 0.f, 0.f);
                float  f = 0.f;
                if (n < NKEYS) {
                    v = *reinterpret_cast<const float4*>(kbase + (size_t)n * DK + kc + k4);
                    f = fbase[n];
                }
                Ks[k4 + 0][nl] = v.x * f;
                Ks[k4 + 1][nl] = v.y * f;
                Ks[k4 + 2][nl] = v.z * f;
                Ks[k4 + 3][nl] = v.w * f;
            }
            __syncthreads();
            #pragma unroll 8
            for (int k = 0; k < KC; ++k) {
                const float4 qa = *reinterpret_cast<const float4*>(&Qs[k][ty * 4]);
                const float4 qb = *reinterpret_cast<const float4*>(&Qs[k][ty * 4 + 64]);
                const float4 ka = *reinterpret_cast<const float4*>(&Ks[k][tx * 4]);
                const float4 kb = *reinterpret_cast<const float4*>(&Ks[k][tx * 4 + 64]);
                const float qv[8] = {qa.x, qa.y, qa.z, qa.w, qb.x, qb.y, qb.z, qb.w};
                const float kv[8] = {ka.x, ka.y, ka.z, ka.w, kb.x, kb.y, kb.z, kb.w};
                #pragma unroll
                for (int bj = 0; bj < 8; ++bj)
                    #pragma unroll
                    for (int nj = 0; nj < 8; ++nj)
                        acc[bj][nj] = fmaf(qv[bj], kv[nj], acc[bj][nj]);
            }
        }
    }
    #pragma unroll
    for (int bj = 0; bj < 8; ++bj) {
        const int b = b0 + ty * 4 + (bj & 3) + (bj >> 2) * 64;
        #pragma unroll
        for (int nj = 0; nj < 8; ++nj) {
            const int n = n0 + tx * 4 + (nj & 3) + (nj >> 2) * 64;
            if (n < NKEYS)
                C[(size_t)b * NKEYS + n] = __float2bfloat16(acc[bj][nj]);
        }
    }
}

// ---------------------------------------------------------------------------
// Pass C (per row b): histogram -> threshold (32nd value bin - margin) ->
// compact candidates -> fp64 exact re-rank -> exact top-32 (ties: low index)
// -> alphas. Margin 4e-3 >> bf16 quantization (~6e-4) + bin width (4.9e-4).
// ---------------------------------------------------------------------------
#define NBIN 4096
#define MAXC 2048
#define MARGIN 4e-3f

__global__ __launch_bounds__(256) void pass_c_kernel(
    const __hip_bfloat16* __restrict__ C, const float* __restrict__ keys,
    const float* __restrict__ QT, const float* __restrict__ F,
    const float* __restrict__ tau_p, const float* __restrict__ lam_p,
    const unsigned char* __restrict__ warm_p, float* __restrict__ out)
{
    const int b = blockIdx.x;
    const int tid = threadIdx.x;
    __shared__ unsigned int hist[NBIN];
    __shared__ double cval[MAXC];
    __shared__ int cidx[MAXC];
    __shared__ int cnt;
    __shared__ float thr;
    __shared__ double red_v[256];
    __shared__ int red_i[256];
    __shared__ int red_p[256];
    __shared__ double topv[KMAX];
    __shared__ int topi[KMAX];

    for (int i = tid; i < NBIN; i += 256) hist[i] = 0u;
    if (tid == 0) cnt = 0;
    __syncthreads();

    const __hip_bfloat16* crow = C + (size_t)b * NKEYS;
    for (int i = tid; i < NKEYS; i += 256) {
        const float v = __bfloat162float(crow[i]);
        int bin = (int)((v + 1.0f) * (NBIN / 2));
        bin = min(max(bin, 0), NBIN - 1);
        atomicAdd(&hist[bin], 1u);
    }
    __syncthreads();
    if (tid == 0) {
        unsigned int cum = 0;
        int t = NBIN - 1;
        for (; t > 0; --t) { cum += hist[t]; if (cum >= KMAX) break; }
        thr = (float)t * (2.0f / NBIN) - 1.0f - MARGIN;
    }
    __syncthreads();
    const float ct = thr;
    for (int i = tid; i < NKEYS; i += 256) {
        const float v = __bfloat162float(crow[i]);
        if (v >= ct) {
            const int p = atomicAdd(&cnt, 1);
            if (p < MAXC) cidx[p] = i;
        }
    }
    __syncthreads();
    const int m = min(cnt, MAXC);

    // fp64 exact re-rank: one candidate per wave; 64 lanes = 8 aspects x 8 kgroups
    const int wave = tid >> 6, lane = tid & 63;
    const int si = lane >> 3, kg = lane & 7;
    for (int c = wave; c < m; c += 4) {
        const int n = cidx[c];
        const float f = F[(size_t)si * NKEYS + n];
        const float* krow = keys + ((size_t)si * NKEYS + n) * DK + kg * 16;
        const float4 k0 = *reinterpret_cast<const float4*>(krow + 0);
        const float4 k1 = *reinterpret_cast<const float4*>(krow + 4);
        const float4 k2 = *reinterpret_cast<const float4*>(krow + 8);
        const float4 k3 = *reinterpret_cast<const float4*>(krow + 12);
        const float kf[16] = {k0.x, k0.y, k0.z, k0.w, k1.x, k1.y, k1.z, k1.w,
                              k2.x, k2.y, k2.z, k2.w, k3.x, k3.y, k3.z, k3.w};
        double acc = 0.0;
        #pragma unroll
        for (int j = 0; j < 16; ++j) {
            const float q = QT[(size_t)(si * DK + kg * 16 + j) * B_ + b];
            acc += (double)q * ((double)kf[j] * (double)f);
        }
        #pragma unroll
        for (int off = 1; off < 64; off <<= 1) acc += __shfl_xor(acc, off);
        if (lane == 0) cval[c] = acc;
    }
    __syncthreads();

    // exact top-32: descending value, ties -> ascending index (lax.top_k order)
    for (int r = 0; r < KMAX; ++r) {
        double bv = -1e300; int bi = 0x7fffffff; int bp = -1;
        for (int c = tid; c < m; c += 256) {
            const double v = cval[c]; const int ix = cidx[c];
            if (v > bv || (v == bv && ix < bi)) { bv = v; bi = ix; bp = c; }
        }
        red_v[tid] = bv; red_i[tid] = bi; red_p[tid] = bp;
        __syncthreads();
        for (int off = 128; off > 0; off >>= 1) {
            if (tid < off) {
                if (red_v[tid + off] > red_v[tid] ||
                    (red_v[tid + off] == red_v[tid] && red_i[tid + off] < red_i[tid])) {
                    red_v[tid] = red_v[tid + off];
                    red_i[tid] = red_i[tid + off];
                    red_p[tid] = red_p[tid + off];
                }
            }
            __syncthreads();
        }
        if (tid == 0) {
            topv[r] = red_v[0]; topi[r] = red_i[0];
            if (red_p[0] >= 0) cval[red_p[0]] = -1e301;
        }
        __syncthreads();
    }

    if (tid == 0) {
        const float lamv = lam_p[0];
        const float tauv = tau_p[0];
        const bool warm = warm_p[0] != 0;
        float al[KMAX];
        float ssum = 0.f;
        if (warm) {
            const float x0 = (float)topv[0] / 0.1f;
            for (int i = 0; i < KMAX; ++i) {
                const float x = (float)topv[i] / 0.1f;
                const float e = expf(x - x0);
                al[i] = e; ssum += e;
            }
        } else {
            for (int i = 0; i < KMAX; ++i) {
                const float v = (float)topv[i];
                const float g = 1.0f / (1.0f + expf(-(lamv * (v - tauv))));
                const float rr = g * expf(v / 0.1f);
                al[i] = rr; ssum += rr;
            }
        }
        for (int i = 0; i < KMAX; ++i) {
            out[b * KMAX + i] = al[i] / ssum;
            out[B_ * KMAX + b * KMAX + i] = (float)topi[i];
        }
    }
}

// ---------------------------------------------------------------------------
extern "C" void kernel_launch(void* const* d_in, const int* in_sizes, int n_in,
                              void* d_out, int out_size, void* d_ws, size_t ws_size,
                              hipStream_t stream) {
    const float* z    = (const float*)d_in[0];
    const float* keys = (const float*)d_in[1];
    const float* wq   = (const float*)d_in[2];
    const float* aw   = (const float*)d_in[3];
    const float* tau  = (const float*)d_in[4];
    const float* lam  = (const float*)d_in[5];
    const unsigned char* warm = (const unsigned char*)d_in[6];
    float* out = (float*)d_out;

    char* ws = (char*)d_ws;
    float* QT = (float*)ws;                                   // 8*128*256*4 = 1 MB
    float* F  = (float*)(ws + (1 << 20));                     // 800000*4 = 3.2 MB
    __hip_bfloat16* C = (__hip_bfloat16*)(ws + (1 << 20) + 3200000); // 51.2 MB

    pass_a_kernel<<<dim3(B_, S_), 128, 0, stream>>>(z, wq, QT);
    pass_k_kernel<<<dim3((S_ * NKEYS) / 16), 256, 0, stream>>>(keys, aw, F);
    pass_b_kernel<<<dim3((NKEYS + NT - 1) / NT, B_ / BT), 256, 0, stream>>>(keys, QT, F, C);
    pass_c_kernel<<<dim3(B_), 256, 0, stream>>>(C, keys, QT, F, tau, lam, warm, out);
}

// Round 2
// 927.316 us; speedup vs baseline: 1.4394x; 1.4394x over previous
//
#include <hip/hip_runtime.h>
#include <hip/hip_bf16.h>
#include <math.h>

#define B_      256
#define DA      1024
#define S_      8
#define DK      128
#define NKEYS   100000
#define KMAX    32
#define KTOT    1024            // S_*DK flattened reduction dim
#define BN      64              // n-tile per block (pass_b)
#define BK      64              // k per LDS step; LDS row = 128 B
#define NBLK    ((NKEYS + BN - 1) / BN)

typedef __attribute__((ext_vector_type(8))) short short8;
typedef __attribute__((ext_vector_type(4))) float f32x4;

typedef const __attribute__((address_space(1))) unsigned gu32;
typedef __attribute__((address_space(3))) unsigned lu32;
#define GLOAD_LDS16(g, s) __builtin_amdgcn_global_load_lds((gu32*)(g), (lu32*)(s), 16, 0, 0)

// ---------------------------------------------------------------------------
// Pass A: queries = einsum('ska,ba->bsk', W_Q, z), L2-normalized (fp64 acc).
// Outputs: QT[s][k][b] fp32 (for exact re-rank) and Qb[b][s*128+k] bf16 (MFMA A).
// ---------------------------------------------------------------------------
__global__ __launch_bounds__(128) void pass_a_kernel(
    const float* __restrict__ z, const float* __restrict__ wq,
    float* __restrict__ QT, __hip_bfloat16* __restrict__ Qb)
{
    const int b = blockIdx.x;
    const int s = blockIdx.y;
    __shared__ float zsh[DA];
    for (int i = threadIdx.x; i < DA; i += 128) zsh[i] = z[b * DA + i];
    __syncthreads();
    const int k = threadIdx.x;
    const float* wrow = wq + (size_t)(s * DK + k) * DA;
    double acc = 0.0;
    #pragma unroll 4
    for (int a = 0; a < DA; a += 4) {
        const float4 w4 = *reinterpret_cast<const float4*>(wrow + a);
        acc += (double)w4.x * (double)zsh[a + 0];
        acc += (double)w4.y * (double)zsh[a + 1];
        acc += (double)w4.z * (double)zsh[a + 2];
        acc += (double)w4.w * (double)zsh[a + 3];
    }
    double sq = acc * acc;
    #pragma unroll
    for (int off = 32; off > 0; off >>= 1) sq += __shfl_down(sq, off);
    __shared__ double part[2];
    if ((threadIdx.x & 63) == 0) part[threadIdx.x >> 6] = sq;
    __syncthreads();
    const double ss  = part[0] + part[1];
    const double inv = 1.0 / (sqrt(ss) + 1e-8);
    const float qv = (float)(acc * inv);
    QT[(size_t)(s * DK + k) * B_ + b] = qv;
    Qb[(size_t)b * KTOT + s * DK + k] = __float2bfloat16(qv);
}

// ---------------------------------------------------------------------------
// Pass K: F[s][n] = softmax(aspect_weights)[s] / (||pool_keys[s,n,:]|| + eps)
// ---------------------------------------------------------------------------
__global__ __launch_bounds__(256) void pass_k_kernel(
    const float* __restrict__ keys, const float* __restrict__ aw,
    float* __restrict__ F)
{
    float e[S_];
    float mx = aw[0];
    #pragma unroll
    for (int i = 1; i < S_; ++i) mx = fmaxf(mx, aw[i]);
    float se = 0.f;
    #pragma unroll
    for (int i = 0; i < S_; ++i) { e[i] = expf(aw[i] - mx); se += e[i]; }

    const int g = threadIdx.x >> 4, l = threadIdx.x & 15;
    const long long sn = (long long)blockIdx.x * 16 + g;
    const float* row = keys + (size_t)sn * DK + l * 8;
    const float4 r0 = *reinterpret_cast<const float4*>(row + 0);
    const float4 r1 = *reinterpret_cast<const float4*>(row + 4);
    double sq = (double)r0.x * r0.x + (double)r0.y * r0.y +
                (double)r0.z * r0.z + (double)r0.w * r0.w +
                (double)r1.x * r1.x + (double)r1.y * r1.y +
                (double)r1.z * r1.z + (double)r1.w * r1.w;
    #pragma unroll
    for (int off = 1; off < 16; off <<= 1) sq += __shfl_xor(sq, off);
    if (l == 0) {
        const int s = (int)(sn / NKEYS);
        const float w = e[s] / se;
        F[sn] = (float)((double)w / (sqrt(sq) + 1e-8));
    }
}

// ---------------------------------------------------------------------------
// Pass B: coarse scores C[b][n] = sum_k Qb[b][k] * (keys*F)[n][k], bf16 MFMA.
// Block: 256 thr / 4 waves; tile 256b x 64n; BK=64; 16 K-steps.
// A staged via global_load_lds (linear dest, inverse-swizzled source);
// B reg-staged fp32->bf16*F with swizzled ds_write. XOR slot swizzle (row&7).
// ---------------------------------------------------------------------------
__global__ __launch_bounds__(256) void pass_b_kernel(
    const float* __restrict__ keys, const __hip_bfloat16* __restrict__ Qb,
    const float* __restrict__ F, __hip_bfloat16* __restrict__ C)
{
    __shared__ __align__(16) char smem[40960];   // A: [0,32768)  B: [32768,40960)
    const int n0 = blockIdx.x * BN;
    const int tid = threadIdx.x;
    const int w = tid >> 6, l = tid & 63;
    const int ln = l & 15, lk = l >> 4;

    f32x4 acc[4][4];
    #pragma unroll
    for (int i = 0; i < 4; ++i)
        #pragma unroll
        for (int j = 0; j < 4; ++j) acc[i][j] = (f32x4){0.f, 0.f, 0.f, 0.f};

    const char* qb = (const char*)Qb;

    for (int kc = 0; kc < KTOT; kc += BK) {
        const int sidx = kc >> 7;          // aspect
        const int kl   = kc & (DK - 1);    // k offset within aspect
        __syncthreads();
        // ---- stage A (32 KB): 32 wave-issues of 1 KB, pre-swizzled source ----
        #pragma unroll
        for (int i = 0; i < 8; ++i) {
            const int j  = w + 4 * i;               // wave-uniform 0..31
            const int bq = j * 8 + (l >> 3);
            const int sl = l & 7;
            const char* g = qb + ((size_t)bq * KTOT + kc + ((sl ^ (bq & 7)) << 3)) * 2;
            GLOAD_LDS16(g, smem + j * 1024);
        }
        // ---- stage B (8 KB): fp32 load, *F, cvt bf16, swizzled ds_write ----
        const float* kbase = keys + (size_t)sidx * NKEYS * DK + kl;
        const float* fbase = F + (size_t)sidx * NKEYS;
        #pragma unroll
        for (int c = 0; c < 2; ++c) {
            const int u  = tid + c * 256;           // 0..511 slots
            const int nr = u >> 3, sl = u & 7;
            const int gn = n0 + nr;
            float f = 0.f;
            float4 v0 = {0, 0, 0, 0}, v1 = {0, 0, 0, 0};
            if (gn < NKEYS) {
                f = fbase[gn];
                const float* kr = kbase + (size_t)gn * DK + sl * 8;
                v0 = *reinterpret_cast<const float4*>(kr);
                v1 = *reinterpret_cast<const float4*>(kr + 4);
            }
            const float vv[8] = {v0.x, v0.y, v0.z, v0.w, v1.x, v1.y, v1.z, v1.w};
            short8 pk;
            #pragma unroll
            for (int e = 0; e < 8; ++e) {
                __hip_bfloat16 h = __float2bfloat16(vv[e] * f);
                pk[e] = *reinterpret_cast<short*>(&h);
            }
            *reinterpret_cast<short8*>(smem + 32768 + nr * 128 + ((sl ^ (nr & 7)) << 4)) = pk;
        }
        __syncthreads();
        // ---- compute: 16 ds_read_b128 + 32 MFMA per wave ----
        #pragma unroll
        for (int kw = 0; kw < 2; ++kw) {
            const int slot = kw * 4 + lk;
            short8 af[4], bf[4];
            #pragma unroll
            for (int mi = 0; mi < 4; ++mi) {
                const int bq = w * 64 + mi * 16 + ln;
                af[mi] = *reinterpret_cast<const short8*>(smem + bq * 128 + ((slot ^ (bq & 7)) << 4));
            }
            #pragma unroll
            for (int nf = 0; nf < 4; ++nf) {
                const int nr = nf * 16 + ln;
                bf[nf] = *reinterpret_cast<const short8*>(smem + 32768 + nr * 128 + ((slot ^ (nr & 7)) << 4));
            }
            #pragma unroll
            for (int mi = 0; mi < 4; ++mi)
                #pragma unroll
                for (int nf = 0; nf < 4; ++nf)
                    acc[mi][nf] = __builtin_amdgcn_mfma_f32_16x16x32_bf16(
                        af[mi], bf[nf], acc[mi][nf], 0, 0, 0);
        }
    }
    // ---- C store: row=(lane>>4)*4+reg, col=lane&15 (m89-verified layout) ----
    #pragma unroll
    for (int mi = 0; mi < 4; ++mi) {
        #pragma unroll
        for (int nf = 0; nf < 4; ++nf) {
            const int n = n0 + nf * 16 + ln;
            if (n < NKEYS) {
                #pragma unroll
                for (int r = 0; r < 4; ++r) {
                    const int bq = w * 64 + mi * 16 + lk * 4 + r;
                    C[(size_t)bq * NKEYS + n] = __float2bfloat16(acc[mi][nf][r]);
                }
            }
        }
    }
}

// ---------------------------------------------------------------------------
// Pass C: per row -- mean/var scan, tail-only histogram (atomic-light),
// threshold-margin compact, fp64 exact re-rank, single-wave top-32, alphas.
// ---------------------------------------------------------------------------
#define MAXC 2048
#define MARGIN 1e-2f
#define HB 1024

__global__ __launch_bounds__(256) void pass_c_kernel(
    const __hip_bfloat16* __restrict__ C, const float* __restrict__ keys,
    const float* __restrict__ QT, const float* __restrict__ F,
    const float* __restrict__ tau_p, const float* __restrict__ lam_p,
    const unsigned char* __restrict__ warm_p, float* __restrict__ out)
{
    const int b = blockIdx.x, tid = threadIdx.x;
    __shared__ float red[16];
    __shared__ unsigned hist[HB];
    __shared__ double cval[MAXC];
    __shared__ int cidx[MAXC];
    __shared__ int cnt;
    __shared__ float sh_thr;
    __shared__ float sh_stat[2];
    __shared__ double topv[KMAX];
    __shared__ int topi[KMAX];

    const __hip_bfloat16* crow = C + (size_t)b * NKEYS;

    // scan 1: mean / var (atomic-free)
    float sm = 0.f, sq = 0.f;
    for (int i = tid; i < NKEYS; i += 256) {
        const float v = __bfloat162float(crow[i]);
        sm += v; sq += v * v;
    }
    #pragma unroll
    for (int off = 32; off > 0; off >>= 1) {
        sm += __shfl_down(sm, off);
        sq += __shfl_down(sq, off);
    }
    if ((tid & 63) == 0) { red[tid >> 6] = sm; red[4 + (tid >> 6)] = sq; }
    __syncthreads();
    if (tid == 0) {
        const float S1 = red[0] + red[1] + red[2] + red[3];
        const float S2 = red[4] + red[5] + red[6] + red[7];
        const float mu = S1 / NKEYS;
        sh_stat[0] = mu;
        sh_stat[1] = sqrtf(fmaxf(S2 / NKEYS - mu * mu, 1e-12f));
    }
    __syncthreads();
    const float mu = sh_stat[0], sg = sh_stat[1];
    const float t1 = mu + 2.5f * sg;

    // scan 2: count tail
    float cc = 0.f;
    for (int i = tid; i < NKEYS; i += 256)
        if (__bfloat162float(crow[i]) >= t1) cc += 1.f;
    #pragma unroll
    for (int off = 32; off > 0; off >>= 1) cc += __shfl_down(cc, off);
    if ((tid & 63) == 0) red[8 + (tid >> 6)] = cc;
    __syncthreads();
    const float c1 = red[8] + red[9] + red[10] + red[11];

    float lo, wd;
    if (c1 >= (float)KMAX) { lo = t1; wd = (8.f * sg) / HB; }
    else                   { lo = -1.1f; wd = 2.2f / HB; }   // unreachable fallback
    const float iw = 1.f / wd;

    for (int i = tid; i < HB; i += 256) hist[i] = 0u;
    if (tid == 0) cnt = 0;
    __syncthreads();
    // scan 3: tail-only histogram (~620 atomics over 1024 bins)
    for (int i = tid; i < NKEYS; i += 256) {
        const float v = __bfloat162float(crow[i]);
        if (v >= lo) {
            const int bin = (int)fminf((v - lo) * iw, (float)(HB - 1));
            atomicAdd(&hist[bin], 1u);
        }
    }
    __syncthreads();
    if (tid == 0) {
        unsigned cum = 0; int t = HB - 1;
        for (; t > 0; --t) { cum += hist[t]; if (cum >= KMAX) break; }
        sh_thr = lo + (float)t * wd - MARGIN;
    }
    __syncthreads();
    const float ct = sh_thr;
    // scan 4: compact candidates
    for (int i = tid; i < NKEYS; i += 256) {
        if (__bfloat162float(crow[i]) >= ct) {
            const int p = atomicAdd(&cnt, 1);
            if (p < MAXC) cidx[p] = i;
        }
    }
    __syncthreads();
    const int m = min(cnt, MAXC);

    // fp64 exact re-rank: one candidate per wave
    const int wave = tid >> 6, lane = tid & 63;
    const int si = lane >> 3, kg = lane & 7;
    for (int c = wave; c < m; c += 4) {
        const int n = cidx[c];
        const float f = F[(size_t)si * NKEYS + n];
        const float* krow = keys + ((size_t)si * NKEYS + n) * DK + kg * 16;
        const float4 k0 = *reinterpret_cast<const float4*>(krow + 0);
        const float4 k1 = *reinterpret_cast<const float4*>(krow + 4);
        const float4 k2 = *reinterpret_cast<const float4*>(krow + 8);
        const float4 k3 = *reinterpret_cast<const float4*>(krow + 12);
        const float kf[16] = {k0.x, k0.y, k0.z, k0.w, k1.x, k1.y, k1.z, k1.w,
                              k2.x, k2.y, k2.z, k2.w, k3.x, k3.y, k3.z, k3.w};
        double acc = 0.0;
        #pragma unroll
        for (int j = 0; j < 16; ++j) {
            const float q = QT[(size_t)(si * DK + kg * 16 + j) * B_ + b];
            acc += (double)q * ((double)kf[j] * (double)f);
        }
        #pragma unroll
        for (int off = 1; off < 64; off <<= 1) acc += __shfl_xor(acc, off);
        if (lane == 0) cval[c] = acc;
    }
    __syncthreads();

    // single-wave exact top-32 (desc value, ties -> asc index), no barriers
    if (tid < 64) {
        for (int r = 0; r < KMAX; ++r) {
            double bv = -1e300; int bi = 0x7fffffff; int bp = -1;
            for (int c = tid; c < m; c += 64) {
                const double v = cval[c]; const int ix = cidx[c];
                if (v > bv || (v == bv && ix < bi)) { bv = v; bi = ix; bp = c; }
            }
            #pragma unroll
            for (int off = 32; off > 0; off >>= 1) {
                const double ov = __shfl_xor(bv, off);
                const int oi = __shfl_xor(bi, off);
                const int op = __shfl_xor(bp, off);
                if (ov > bv || (ov == bv && oi < bi)) { bv = ov; bi = oi; bp = op; }
            }
            if (tid == 0) { topv[r] = bv; topi[r] = bi; if (bp >= 0) cval[bp] = -1e301; }
        }
        if (tid == 0) {
            const float lamv = lam_p[0];
            const float tauv = tau_p[0];
            const bool warm = warm_p[0] != 0;
            float al[KMAX];
            float ssum = 0.f;
            if (warm) {
                const float x0 = (float)topv[0] / 0.1f;
                for (int i = 0; i < KMAX; ++i) {
                    const float e = expf((float)topv[i] / 0.1f - x0);
                    al[i] = e; ssum += e;
                }
            } else {
                for (int i = 0; i < KMAX; ++i) {
                    const float v = (float)topv[i];
                    const float g = 1.0f / (1.0f + expf(-(lamv * (v - tauv))));
                    const float rr = g * expf(v / 0.1f);
                    al[i] = rr; ssum += rr;
                }
            }
            for (int i = 0; i < KMAX; ++i) {
                out[b * KMAX + i] = al[i] / ssum;
                out[B_ * KMAX + b * KMAX + i] = (float)topi[i];
            }
        }
    }
}

// ---------------------------------------------------------------------------
extern "C" void kernel_launch(void* const* d_in, const int* in_sizes, int n_in,
                              void* d_out, int out_size, void* d_ws, size_t ws_size,
                              hipStream_t stream) {
    const float* z    = (const float*)d_in[0];
    const float* keys = (const float*)d_in[1];
    const float* wq   = (const float*)d_in[2];
    const float* aw   = (const float*)d_in[3];
    const float* tau  = (const float*)d_in[4];
    const float* lam  = (const float*)d_in[5];
    const unsigned char* warm = (const unsigned char*)d_in[6];
    float* out = (float*)d_out;

    char* ws = (char*)d_ws;
    float* QT           = (float*)ws;                       // @0      1.0 MB
    float* F            = (float*)(ws + (1 << 20));         // @1MB    3.2 MB
    __hip_bfloat16* Qb  = (__hip_bfloat16*)(ws + (8 << 20));  // @8MB  0.5 MB
    __hip_bfloat16* C   = (__hip_bfloat16*)(ws + (16 << 20)); // @16MB 51.2 MB

    pass_a_kernel<<<dim3(B_, S_), 128, 0, stream>>>(z, wq, QT, Qb);
    pass_k_kernel<<<dim3((S_ * NKEYS) / 16), 256, 0, stream>>>(keys, aw, F);
    pass_b_kernel<<<dim3(NBLK), 256, 0, stream>>>(keys, Qb, F, C);
    pass_c_kernel<<<dim3(B_), 256, 0, stream>>>(C, keys, QT, F, tau, lam, warm, out);
}

// Round 3
// 555.981 us; speedup vs baseline: 2.4007x; 1.6679x over previous
//
#include <hip/hip_runtime.h>
#include <hip/hip_bf16.h>
#include <math.h>

#define B_      256
#define DA      1024
#define S_      8
#define DK      128
#define NKEYS   100000
#define KMAX    32
#define KTOT    1024            // S_*DK flattened reduction dim
#define BN      64              // n-tile per block (pass_b)
#define BK      64              // k per LDS step; LDS row = 128 B
#define NBLK    ((NKEYS + BN - 1) / BN)

typedef __attribute__((ext_vector_type(8))) short short8;
typedef __attribute__((ext_vector_type(4))) float f32x4;

typedef const __attribute__((address_space(1))) unsigned gu32;
typedef __attribute__((address_space(3))) unsigned lu32;
#define GLOAD_LDS16(g, s) __builtin_amdgcn_global_load_lds((gu32*)(g), (lu32*)(s), 16, 0, 0)

__device__ __forceinline__ float bf16_up(short h) {
    union { unsigned u; float f; } cv;
    cv.u = ((unsigned)(unsigned short)h) << 16;
    return cv.f;
}

// ---------------------------------------------------------------------------
// Pass A: queries = einsum('ska,ba->bsk', W_Q, z), L2-normalized (fp64 acc).
// Outputs: QT[s][k][b] fp32 (for exact re-rank) and Qb[b][s*128+k] bf16 (MFMA A).
// ---------------------------------------------------------------------------
__global__ __launch_bounds__(128) void pass_a_kernel(
    const float* __restrict__ z, const float* __restrict__ wq,
    float* __restrict__ QT, __hip_bfloat16* __restrict__ Qb)
{
    const int b = blockIdx.x;
    const int s = blockIdx.y;
    __shared__ float zsh[DA];
    for (int i = threadIdx.x; i < DA; i += 128) zsh[i] = z[b * DA + i];
    __syncthreads();
    const int k = threadIdx.x;
    const float* wrow = wq + (size_t)(s * DK + k) * DA;
    double acc = 0.0;
    #pragma unroll 4
    for (int a = 0; a < DA; a += 4) {
        const float4 w4 = *reinterpret_cast<const float4*>(wrow + a);
        acc += (double)w4.x * (double)zsh[a + 0];
        acc += (double)w4.y * (double)zsh[a + 1];
        acc += (double)w4.z * (double)zsh[a + 2];
        acc += (double)w4.w * (double)zsh[a + 3];
    }
    double sq = acc * acc;
    #pragma unroll
    for (int off = 32; off > 0; off >>= 1) sq += __shfl_down(sq, off);
    __shared__ double part[2];
    if ((threadIdx.x & 63) == 0) part[threadIdx.x >> 6] = sq;
    __syncthreads();
    const double ss  = part[0] + part[1];
    const double inv = 1.0 / (sqrt(ss) + 1e-8);
    const float qv = (float)(acc * inv);
    QT[(size_t)(s * DK + k) * B_ + b] = qv;
    Qb[(size_t)b * KTOT + s * DK + k] = __float2bfloat16(qv);
}

// ---------------------------------------------------------------------------
// Pass K: F[s][n] = softmax(aspect_weights)[s] / (||pool_keys[s,n,:]|| + eps)
// ---------------------------------------------------------------------------
__global__ __launch_bounds__(256) void pass_k_kernel(
    const float* __restrict__ keys, const float* __restrict__ aw,
    float* __restrict__ F)
{
    float e[S_];
    float mx = aw[0];
    #pragma unroll
    for (int i = 1; i < S_; ++i) mx = fmaxf(mx, aw[i]);
    float se = 0.f;
    #pragma unroll
    for (int i = 0; i < S_; ++i) { e[i] = expf(aw[i] - mx); se += e[i]; }

    const int g = threadIdx.x >> 4, l = threadIdx.x & 15;
    const long long sn = (long long)blockIdx.x * 16 + g;
    const float* row = keys + (size_t)sn * DK + l * 8;
    const float4 r0 = *reinterpret_cast<const float4*>(row + 0);
    const float4 r1 = *reinterpret_cast<const float4*>(row + 4);
    double sq = (double)r0.x * r0.x + (double)r0.y * r0.y +
                (double)r0.z * r0.z + (double)r0.w * r0.w +
                (double)r1.x * r1.x + (double)r1.y * r1.y +
                (double)r1.z * r1.z + (double)r1.w * r1.w;
    #pragma unroll
    for (int off = 1; off < 16; off <<= 1) sq += __shfl_xor(sq, off);
    if (l == 0) {
        const int s = (int)(sn / NKEYS);
        const float w = e[s] / se;
        F[sn] = (float)((double)w / (sqrt(sq) + 1e-8));
    }
}

// ---------------------------------------------------------------------------
// Pass B: coarse scores C[b][n] = sum_k Qb[b][k] * (keys*F)[n][k], bf16 MFMA.
// (unchanged from round 2)
// ---------------------------------------------------------------------------
__global__ __launch_bounds__(256) void pass_b_kernel(
    const float* __restrict__ keys, const __hip_bfloat16* __restrict__ Qb,
    const float* __restrict__ F, __hip_bfloat16* __restrict__ C)
{
    __shared__ __align__(16) char smem[40960];   // A: [0,32768)  B: [32768,40960)
    const int n0 = blockIdx.x * BN;
    const int tid = threadIdx.x;
    const int w = tid >> 6, l = tid & 63;
    const int ln = l & 15, lk = l >> 4;

    f32x4 acc[4][4];
    #pragma unroll
    for (int i = 0; i < 4; ++i)
        #pragma unroll
        for (int j = 0; j < 4; ++j) acc[i][j] = (f32x4){0.f, 0.f, 0.f, 0.f};

    const char* qb = (const char*)Qb;

    for (int kc = 0; kc < KTOT; kc += BK) {
        const int sidx = kc >> 7;          // aspect
        const int kl   = kc & (DK - 1);    // k offset within aspect
        __syncthreads();
        // ---- stage A (32 KB): 32 wave-issues of 1 KB, pre-swizzled source ----
        #pragma unroll
        for (int i = 0; i < 8; ++i) {
            const int j  = w + 4 * i;               // wave-uniform 0..31
            const int bq = j * 8 + (l >> 3);
            const int sl = l & 7;
            const char* g = qb + ((size_t)bq * KTOT + kc + ((sl ^ (bq & 7)) << 3)) * 2;
            GLOAD_LDS16(g, smem + j * 1024);
        }
        // ---- stage B (8 KB): fp32 load, *F, cvt bf16, swizzled ds_write ----
        const float* kbase = keys + (size_t)sidx * NKEYS * DK + kl;
        const float* fbase = F + (size_t)sidx * NKEYS;
        #pragma unroll
        for (int c = 0; c < 2; ++c) {
            const int u  = tid + c * 256;           // 0..511 slots
            const int nr = u >> 3, sl = u & 7;
            const int gn = n0 + nr;
            float f = 0.f;
            float4 v0 = {0, 0, 0, 0}, v1 = {0, 0, 0, 0};
            if (gn < NKEYS) {
                f = fbase[gn];
                const float* kr = kbase + (size_t)gn * DK + sl * 8;
                v0 = *reinterpret_cast<const float4*>(kr);
                v1 = *reinterpret_cast<const float4*>(kr + 4);
            }
            const float vv[8] = {v0.x, v0.y, v0.z, v0.w, v1.x, v1.y, v1.z, v1.w};
            short8 pk;
            #pragma unroll
            for (int e = 0; e < 8; ++e) {
                __hip_bfloat16 h = __float2bfloat16(vv[e] * f);
                pk[e] = *reinterpret_cast<short*>(&h);
            }
            *reinterpret_cast<short8*>(smem + 32768 + nr * 128 + ((sl ^ (nr & 7)) << 4)) = pk;
        }
        __syncthreads();
        // ---- compute: 16 ds_read_b128 + 32 MFMA per wave ----
        #pragma unroll
        for (int kw = 0; kw < 2; ++kw) {
            const int slot = kw * 4 + lk;
            short8 af[4], bf[4];
            #pragma unroll
            for (int mi = 0; mi < 4; ++mi) {
                const int bq = w * 64 + mi * 16 + ln;
                af[mi] = *reinterpret_cast<const short8*>(smem + bq * 128 + ((slot ^ (bq & 7)) << 4));
            }
            #pragma unroll
            for (int nf = 0; nf < 4; ++nf) {
                const int nr = nf * 16 + ln;
                bf[nf] = *reinterpret_cast<const short8*>(smem + 32768 + nr * 128 + ((slot ^ (nr & 7)) << 4));
            }
            #pragma unroll
            for (int mi = 0; mi < 4; ++mi)
                #pragma unroll
                for (int nf = 0; nf < 4; ++nf)
                    acc[mi][nf] = __builtin_amdgcn_mfma_f32_16x16x32_bf16(
                        af[mi], bf[nf], acc[mi][nf], 0, 0, 0);
        }
    }
    // ---- C store: row=(lane>>4)*4+reg, col=lane&15 (m89-verified layout) ----
    #pragma unroll
    for (int mi = 0; mi < 4; ++mi) {
        #pragma unroll
        for (int nf = 0; nf < 4; ++nf) {
            const int n = n0 + nf * 16 + ln;
            if (n < NKEYS) {
                #pragma unroll
                for (int r = 0; r < 4; ++r) {
                    const int bq = w * 64 + mi * 16 + lk * 4 + r;
                    C[(size_t)bq * NKEYS + n] = __float2bfloat16(acc[mi][nf][r]);
                }
            }
        }
    }
}

// ---------------------------------------------------------------------------
// Pass C (rewritten): 1024 threads/block, one block per row.
// Row loaded ONCE into per-thread registers (13 x short8, static index).
// Phases: stats+max -> adaptive tail histogram (attempt loop, airtight) ->
// compact -> fp64 exact re-rank -> single-wave exact top-32 -> alphas.
// ---------------------------------------------------------------------------
#define MAXC 2048
#define MARGIN 1e-2f
#define HB 1024
#define NV8 12500               // short8's per row (100000/8)
#define CTH 1024                // threads
#define NIT 13                  // ceil(12500/1024)

__global__ __launch_bounds__(1024) void pass_c_kernel(
    const __hip_bfloat16* __restrict__ C, const float* __restrict__ keys,
    const float* __restrict__ QT, const float* __restrict__ F,
    const float* __restrict__ tau_p, const float* __restrict__ lam_p,
    const unsigned char* __restrict__ warm_p, float* __restrict__ out)
{
    const int b = blockIdx.x, tid = threadIdx.x;
    __shared__ float redA[16], redB[16], redC[16];
    __shared__ unsigned hist[HB];
    __shared__ double cval[MAXC];
    __shared__ int cidx[MAXC];
    __shared__ int cnt;
    __shared__ float sh_thr, sh_lo, sh_iw;
    __shared__ int sh_done;
    __shared__ float sh_stat[3];
    __shared__ double topv[KMAX];
    __shared__ int topi[KMAX];

    const __hip_bfloat16* crow = C + (size_t)b * NKEYS;

    // ---- load row once into registers (static indexing; rule #20) ----
    short8 vals[NIT];
    #pragma unroll
    for (int j = 0; j < NIT; ++j) {
        const int i = tid + j * CTH;
        if (i < NV8) vals[j] = *reinterpret_cast<const short8*>(crow + i * 8);
        else { short8 z = {0,0,0,0,0,0,0,0}; vals[j] = z; }  // bf16 0.0 (below any thr)
    }

    // ---- phase 1: mean / var / max from registers ----
    float sm = 0.f, sq = 0.f, mx = -2.f;
    #pragma unroll
    for (int j = 0; j < NIT; ++j) {
        const int i = tid + j * CTH;
        if (i < NV8) {
            #pragma unroll
            for (int e = 0; e < 8; ++e) {
                const float v = bf16_up(vals[j][e]);
                sm += v; sq += v * v; mx = fmaxf(mx, v);
            }
        }
    }
    #pragma unroll
    for (int off = 32; off > 0; off >>= 1) {
        sm += __shfl_down(sm, off);
        sq += __shfl_down(sq, off);
        mx = fmaxf(mx, __shfl_down(mx, off));
    }
    if ((tid & 63) == 0) { redA[tid >> 6] = sm; redB[tid >> 6] = sq; redC[tid >> 6] = mx; }
    __syncthreads();
    if (tid == 0) {
        float S1 = 0.f, S2 = 0.f, M = -2.f;
        #pragma unroll
        for (int i = 0; i < 16; ++i) { S1 += redA[i]; S2 += redB[i]; M = fmaxf(M, redC[i]); }
        const float mu = S1 / NKEYS;
        sh_stat[0] = mu;
        sh_stat[1] = sqrtf(fmaxf(S2 / NKEYS - mu * mu, 1e-12f));
        sh_stat[2] = M;
    }
    __syncthreads();
    const float mu = sh_stat[0], sg = sh_stat[1], rmax = sh_stat[2];

    // ---- phase 2: adaptive tail histogram; attempt-loop is airtight ----
    for (int attempt = 0; attempt < 3; ++attempt) {
        if (tid == 0) {
            float lo = (attempt == 0) ? (mu + 2.5f * sg)
                     : (attempt == 1) ? mu : -1.1f;
            lo = fminf(lo, rmax - 1e-6f);
            const float range = fmaxf(rmax + 1e-6f - lo, 1e-6f);
            sh_lo = lo;
            sh_iw = (float)HB / range;
        }
        for (int i = tid; i < HB; i += CTH) hist[i] = 0u;
        __syncthreads();
        const float lo = sh_lo, iw = sh_iw;
        #pragma unroll
        for (int j = 0; j < NIT; ++j) {
            const int i = tid + j * CTH;
            if (i < NV8) {
                #pragma unroll
                for (int e = 0; e < 8; ++e) {
                    const float v = bf16_up(vals[j][e]);
                    if (v >= lo) {
                        const int bin = min((int)((v - lo) * iw), HB - 1);
                        atomicAdd(&hist[bin], 1u);
                    }
                }
            }
        }
        __syncthreads();
        if (tid == 0) {
            unsigned cum = 0; int t = HB - 1;
            for (; t >= 0; --t) { cum += hist[t]; if (cum >= KMAX) break; }
            if (cum >= KMAX) {
                sh_thr = lo + (float)t / sh_iw - MARGIN;
                sh_done = 1;
            } else sh_done = 0;
        }
        __syncthreads();
        if (sh_done) break;
    }

    // ---- phase 3: compact candidates (from registers) ----
    if (tid == 0) cnt = 0;
    __syncthreads();
    const float ct = sh_thr;
    #pragma unroll
    for (int j = 0; j < NIT; ++j) {
        const int i = tid + j * CTH;
        if (i < NV8) {
            #pragma unroll
            for (int e = 0; e < 8; ++e) {
                if (bf16_up(vals[j][e]) >= ct) {
                    const int p = atomicAdd(&cnt, 1);
                    if (p < MAXC) cidx[p] = i * 8 + e;
                }
            }
        }
    }
    __syncthreads();
    const int m = min(cnt, MAXC);

    // ---- phase 4: fp64 exact re-rank, one candidate per wave (16 waves) ----
    const int wave = tid >> 6, lane = tid & 63;
    const int si = lane >> 3, kg = lane & 7;
    for (int c = wave; c < m; c += 16) {
        const int n = cidx[c];
        const float f = F[(size_t)si * NKEYS + n];
        const float* krow = keys + ((size_t)si * NKEYS + n) * DK + kg * 16;
        const float4 k0 = *reinterpret_cast<const float4*>(krow + 0);
        const float4 k1 = *reinterpret_cast<const float4*>(krow + 4);
        const float4 k2 = *reinterpret_cast<const float4*>(krow + 8);
        const float4 k3 = *reinterpret_cast<const float4*>(krow + 12);
        const float kf[16] = {k0.x, k0.y, k0.z, k0.w, k1.x, k1.y, k1.z, k1.w,
                              k2.x, k2.y, k2.z, k2.w, k3.x, k3.y, k3.z, k3.w};
        double acc = 0.0;
        #pragma unroll
        for (int j = 0; j < 16; ++j) {
            const float q = QT[(size_t)(si * DK + kg * 16 + j) * B_ + b];
            acc += (double)q * ((double)kf[j] * (double)f);
        }
        #pragma unroll
        for (int off = 1; off < 64; off <<= 1) acc += __shfl_xor(acc, off);
        if (lane == 0) cval[c] = acc;
    }
    __syncthreads();

    // ---- phase 5: single-wave exact top-32 (desc value, ties -> asc index) ----
    if (tid < 64) {
        for (int r = 0; r < KMAX; ++r) {
            double bv = -1e300; int bi = 0x7fffffff; int bp = -1;
            for (int c = tid; c < m; c += 64) {
                const double v = cval[c]; const int ix = cidx[c];
                if (v > bv || (v == bv && ix < bi)) { bv = v; bi = ix; bp = c; }
            }
            #pragma unroll
            for (int off = 32; off > 0; off >>= 1) {
                const double ov = __shfl_xor(bv, off);
                const int oi = __shfl_xor(bi, off);
                const int op = __shfl_xor(bp, off);
                if (ov > bv || (ov == bv && oi < bi)) { bv = ov; bi = oi; bp = op; }
            }
            if (tid == 0) { topv[r] = bv; topi[r] = bi; if (bp >= 0) cval[bp] = -1e301; }
        }
        if (tid == 0) {
            const float lamv = lam_p[0];
            const float tauv = tau_p[0];
            const bool warm = warm_p[0] != 0;
            float al[KMAX];
            float ssum = 0.f;
            if (warm) {
                const float x0 = (float)topv[0] / 0.1f;
                for (int i = 0; i < KMAX; ++i) {
                    const float e = expf((float)topv[i] / 0.1f - x0);
                    al[i] = e; ssum += e;
                }
            } else {
                for (int i = 0; i < KMAX; ++i) {
                    const float v = (float)topv[i];
                    const float g = 1.0f / (1.0f + expf(-(lamv * (v - tauv))));
                    const float rr = g * expf(v / 0.1f);
                    al[i] = rr; ssum += rr;
                }
            }
            for (int i = 0; i < KMAX; ++i) {
                out[b * KMAX + i] = al[i] / ssum;
                out[B_ * KMAX + b * KMAX + i] = (float)topi[i];
            }
        }
    }
}

// ---------------------------------------------------------------------------
extern "C" void kernel_launch(void* const* d_in, const int* in_sizes, int n_in,
                              void* d_out, int out_size, void* d_ws, size_t ws_size,
                              hipStream_t stream) {
    const float* z    = (const float*)d_in[0];
    const float* keys = (const float*)d_in[1];
    const float* wq   = (const float*)d_in[2];
    const float* aw   = (const float*)d_in[3];
    const float* tau  = (const float*)d_in[4];
    const float* lam  = (const float*)d_in[5];
    const unsigned char* warm = (const unsigned char*)d_in[6];
    float* out = (float*)d_out;

    char* ws = (char*)d_ws;
    float* QT           = (float*)ws;                       // @0      1.0 MB
    float* F            = (float*)(ws + (1 << 20));         // @1MB    3.2 MB
    __hip_bfloat16* Qb  = (__hip_bfloat16*)(ws + (8 << 20));  // @8MB  0.5 MB
    __hip_bfloat16* C   = (__hip_bfloat16*)(ws + (16 << 20)); // @16MB 51.2 MB

    pass_a_kernel<<<dim3(B_, S_), 128, 0, stream>>>(z, wq, QT, Qb);
    pass_k_kernel<<<dim3((S_ * NKEYS) / 16), 256, 0, stream>>>(keys, aw, F);
    pass_b_kernel<<<dim3(NBLK), 256, 0, stream>>>(keys, Qb, F, C);
    pass_c_kernel<<<dim3(B_), 1024, 0, stream>>>(C, keys, QT, F, tau, lam, warm, out);
}

// Round 4
// 538.049 us; speedup vs baseline: 2.4807x; 1.0333x over previous
//
#include <hip/hip_runtime.h>
#include <hip/hip_bf16.h>
#include <math.h>

#define B_      256
#define DA      1024
#define S_      8
#define DK      128
#define NKEYS   100000
#define KMAX    32
#define KTOT    1024            // S_*DK flattened reduction dim
#define BN      64              // n-tile per block (pass_b)
#define BK      64              // k per LDS step; LDS row = 128 B
#define NBLK    ((NKEYS + BN - 1) / BN)

typedef __attribute__((ext_vector_type(8))) short short8;
typedef __attribute__((ext_vector_type(4))) float f32x4;

typedef const __attribute__((address_space(1))) unsigned gu32;
typedef __attribute__((address_space(3))) unsigned lu32;
#define GLOAD_LDS16(g, s) __builtin_amdgcn_global_load_lds((gu32*)(g), (lu32*)(s), 16, 0, 0)

__device__ __forceinline__ float bf16_up(short h) {
    union { unsigned u; float f; } cv;
    cv.u = ((unsigned)(unsigned short)h) << 16;
    return cv.f;
}

// ---------------------------------------------------------------------------
// Pass A: queries = einsum('ska,ba->bsk', W_Q, z), L2-normalized (fp64 acc).
// Outputs: QT[s][k][b] fp32 (exact re-rank) and Qb[b][s*128+k] bf16 (MFMA A).
// (unchanged -- QT must stay bit-identical across rounds)
// ---------------------------------------------------------------------------
__global__ __launch_bounds__(128) void pass_a_kernel(
    const float* __restrict__ z, const float* __restrict__ wq,
    float* __restrict__ QT, __hip_bfloat16* __restrict__ Qb)
{
    const int b = blockIdx.x;
    const int s = blockIdx.y;
    __shared__ float zsh[DA];
    for (int i = threadIdx.x; i < DA; i += 128) zsh[i] = z[b * DA + i];
    __syncthreads();
    const int k = threadIdx.x;
    const float* wrow = wq + (size_t)(s * DK + k) * DA;
    double acc = 0.0;
    #pragma unroll 4
    for (int a = 0; a < DA; a += 4) {
        const float4 w4 = *reinterpret_cast<const float4*>(wrow + a);
        acc += (double)w4.x * (double)zsh[a + 0];
        acc += (double)w4.y * (double)zsh[a + 1];
        acc += (double)w4.z * (double)zsh[a + 2];
        acc += (double)w4.w * (double)zsh[a + 3];
    }
    double sq = acc * acc;
    #pragma unroll
    for (int off = 32; off > 0; off >>= 1) sq += __shfl_down(sq, off);
    __shared__ double part[2];
    if ((threadIdx.x & 63) == 0) part[threadIdx.x >> 6] = sq;
    __syncthreads();
    const double ss  = part[0] + part[1];
    const double inv = 1.0 / (sqrt(ss) + 1e-8);
    const float qv = (float)(acc * inv);
    QT[(size_t)(s * DK + k) * B_ + b] = qv;
    Qb[(size_t)b * KTOT + s * DK + k] = __float2bfloat16(qv);
}

// ---------------------------------------------------------------------------
// Pass K: F[s][n] = softmax(aw)[s] / (||key||+eps)  (bit-identical to R3) and
// NEW: Kb[s][n][k] = bf16(key[k] * f)  -- folds scale+cvt out of pass_b.
// f recomputed per lane from the butterflied sq: identical fp32 to F[sn].
// ---------------------------------------------------------------------------
__global__ __launch_bounds__(256) void pass_k_kernel(
    const float* __restrict__ keys, const float* __restrict__ aw,
    float* __restrict__ F, __hip_bfloat16* __restrict__ Kb)
{
    float e[S_];
    float mx = aw[0];
    #pragma unroll
    for (int i = 1; i < S_; ++i) mx = fmaxf(mx, aw[i]);
    float se = 0.f;
    #pragma unroll
    for (int i = 0; i < S_; ++i) { e[i] = expf(aw[i] - mx); se += e[i]; }

    const int g = threadIdx.x >> 4, l = threadIdx.x & 15;
    const long long sn = (long long)blockIdx.x * 16 + g;
    const float* row = keys + (size_t)sn * DK + l * 8;
    const float4 r0 = *reinterpret_cast<const float4*>(row + 0);
    const float4 r1 = *reinterpret_cast<const float4*>(row + 4);
    double sq = (double)r0.x * r0.x + (double)r0.y * r0.y +
                (double)r0.z * r0.z + (double)r0.w * r0.w +
                (double)r1.x * r1.x + (double)r1.y * r1.y +
                (double)r1.z * r1.z + (double)r1.w * r1.w;
    #pragma unroll
    for (int off = 1; off < 16; off <<= 1) sq += __shfl_xor(sq, off);
    const int s = (int)(sn / NKEYS);
    const float w = e[s] / se;
    const float f = (float)((double)w / (sqrt(sq) + 1e-8));
    if (l == 0) F[sn] = f;

    const float vv[8] = {r0.x, r0.y, r0.z, r0.w, r1.x, r1.y, r1.z, r1.w};
    short8 pk;
    #pragma unroll
    for (int ee = 0; ee < 8; ++ee) {
        __hip_bfloat16 h = __float2bfloat16(vv[ee] * f);
        pk[ee] = *reinterpret_cast<short*>(&h);
    }
    *reinterpret_cast<short8*>((__hip_bfloat16*)Kb + (size_t)sn * DK + l * 8) = pk;
}

// ---------------------------------------------------------------------------
// Pass B: coarse scores C[b][n] = sum_k Qb[b][k] * Kb[n][k], bf16 MFMA.
// Pure gload_lds staging (A and B), no reg staging / cvt / ds_write.
// Tile 256b x 64n, BK=64, 16 K-steps, 2-barrier loop, 40 KB LDS (4 blk/CU).
// ---------------------------------------------------------------------------
__global__ __launch_bounds__(256) void pass_b_kernel(
    const __hip_bfloat16* __restrict__ Kb, const __hip_bfloat16* __restrict__ Qb,
    __hip_bfloat16* __restrict__ C)
{
    __shared__ __align__(16) char smem[40960];   // A: [0,32768)  B: [32768,40960)
    const int n0 = blockIdx.x * BN;
    const int tid = threadIdx.x;
    const int w = tid >> 6, l = tid & 63;
    const int ln = l & 15, lk = l >> 4;

    f32x4 acc[4][4];
    #pragma unroll
    for (int i = 0; i < 4; ++i)
        #pragma unroll
        for (int j = 0; j < 4; ++j) acc[i][j] = (f32x4){0.f, 0.f, 0.f, 0.f};

    const char* qb = (const char*)Qb;
    const char* kb = (const char*)Kb;
    const int sl = l & 7, lr = l >> 3;   // within-chunk slot / row

    for (int kc = 0; kc < KTOT; kc += BK) {
        const int sidx = kc >> 7;          // aspect
        const int kl   = kc & (DK - 1);    // k offset within aspect
        __syncthreads();
        // ---- stage A (32 KB): 32 wave-issues of 1 KB, inverse-swz source ----
        #pragma unroll
        for (int i = 0; i < 8; ++i) {
            const int j  = w + 4 * i;               // chunk 0..31
            const int bq = j * 8 + lr;              // query row 0..255
            const char* g = qb + ((size_t)bq * KTOT + kc + ((sl ^ (bq & 7)) << 3)) * 2;
            GLOAD_LDS16(g, smem + j * 1024);
        }
        // ---- stage B (8 KB): 8 wave-issues of 1 KB, inverse-swz source ----
        #pragma unroll
        for (int i = 0; i < 2; ++i) {
            const int j  = w + 4 * i;               // chunk 0..7
            const int nr = j * 8 + lr;              // tile row 0..63
            const size_t gn = (size_t)sidx * NKEYS + (n0 + nr);  // OOB rows: slack-guarded
            const char* g = kb + (gn * DK + kl + ((sl ^ (nr & 7)) << 3)) * 2;
            GLOAD_LDS16(g, smem + 32768 + j * 1024);
        }
        __syncthreads();
        // ---- compute: 16 ds_read_b128 + 32 MFMA per wave ----
        #pragma unroll
        for (int kw = 0; kw < 2; ++kw) {
            const int slot = kw * 4 + lk;
            short8 af[4], bf[4];
            #pragma unroll
            for (int mi = 0; mi < 4; ++mi) {
                const int bq = w * 64 + mi * 16 + ln;
                af[mi] = *reinterpret_cast<const short8*>(smem + bq * 128 + ((slot ^ (bq & 7)) << 4));
            }
            #pragma unroll
            for (int nf = 0; nf < 4; ++nf) {
                const int nr = nf * 16 + ln;
                bf[nf] = *reinterpret_cast<const short8*>(smem + 32768 + nr * 128 + ((slot ^ (nr & 7)) << 4));
            }
            #pragma unroll
            for (int mi = 0; mi < 4; ++mi)
                #pragma unroll
                for (int nf = 0; nf < 4; ++nf)
                    acc[mi][nf] = __builtin_amdgcn_mfma_f32_16x16x32_bf16(
                        af[mi], bf[nf], acc[mi][nf], 0, 0, 0);
        }
    }
    // ---- C store: row=(lane>>4)*4+reg, col=lane&15 (m89-verified layout) ----
    #pragma unroll
    for (int mi = 0; mi < 4; ++mi) {
        #pragma unroll
        for (int nf = 0; nf < 4; ++nf) {
            const int n = n0 + nf * 16 + ln;
            if (n < NKEYS) {
                #pragma unroll
                for (int r = 0; r < 4; ++r) {
                    const int bq = w * 64 + mi * 16 + lk * 4 + r;
                    C[(size_t)bq * NKEYS + n] = __float2bfloat16(acc[mi][nf][r]);
                }
            }
        }
    }
}

// ---------------------------------------------------------------------------
// Pass C: unchanged from round 3 (exact-rank arithmetic frozen).
// ---------------------------------------------------------------------------
#define MAXC 2048
#define MARGIN 1e-2f
#define HB 1024
#define NV8 12500               // short8's per row (100000/8)
#define CTH 1024                // threads
#define NIT 13                  // ceil(12500/1024)

__global__ __launch_bounds__(1024) void pass_c_kernel(
    const __hip_bfloat16* __restrict__ C, const float* __restrict__ keys,
    const float* __restrict__ QT, const float* __restrict__ F,
    const float* __restrict__ tau_p, const float* __restrict__ lam_p,
    const unsigned char* __restrict__ warm_p, float* __restrict__ out)
{
    const int b = blockIdx.x, tid = threadIdx.x;
    __shared__ float redA[16], redB[16], redC[16];
    __shared__ unsigned hist[HB];
    __shared__ double cval[MAXC];
    __shared__ int cidx[MAXC];
    __shared__ int cnt;
    __shared__ float sh_thr, sh_lo, sh_iw;
    __shared__ int sh_done;
    __shared__ float sh_stat[3];
    __shared__ double topv[KMAX];
    __shared__ int topi[KMAX];

    const __hip_bfloat16* crow = C + (size_t)b * NKEYS;

    // ---- load row once into registers (static indexing; rule #20) ----
    short8 vals[NIT];
    #pragma unroll
    for (int j = 0; j < NIT; ++j) {
        const int i = tid + j * CTH;
        if (i < NV8) vals[j] = *reinterpret_cast<const short8*>(crow + i * 8);
        else { short8 z = {0,0,0,0,0,0,0,0}; vals[j] = z; }
    }

    // ---- phase 1: mean / var / max from registers ----
    float sm = 0.f, sq = 0.f, mx = -2.f;
    #pragma unroll
    for (int j = 0; j < NIT; ++j) {
        const int i = tid + j * CTH;
        if (i < NV8) {
            #pragma unroll
            for (int e = 0; e < 8; ++e) {
                const float v = bf16_up(vals[j][e]);
                sm += v; sq += v * v; mx = fmaxf(mx, v);
            }
        }
    }
    #pragma unroll
    for (int off = 32; off > 0; off >>= 1) {
        sm += __shfl_down(sm, off);
        sq += __shfl_down(sq, off);
        mx = fmaxf(mx, __shfl_down(mx, off));
    }
    if ((tid & 63) == 0) { redA[tid >> 6] = sm; redB[tid >> 6] = sq; redC[tid >> 6] = mx; }
    __syncthreads();
    if (tid == 0) {
        float S1 = 0.f, S2 = 0.f, M = -2.f;
        #pragma unroll
        for (int i = 0; i < 16; ++i) { S1 += redA[i]; S2 += redB[i]; M = fmaxf(M, redC[i]); }
        const float mu = S1 / NKEYS;
        sh_stat[0] = mu;
        sh_stat[1] = sqrtf(fmaxf(S2 / NKEYS - mu * mu, 1e-12f));
        sh_stat[2] = M;
    }
    __syncthreads();
    const float mu = sh_stat[0], sg = sh_stat[1], rmax = sh_stat[2];

    // ---- phase 2: adaptive tail histogram; attempt-loop is airtight ----
    for (int attempt = 0; attempt < 3; ++attempt) {
        if (tid == 0) {
            float lo = (attempt == 0) ? (mu + 2.5f * sg)
                     : (attempt == 1) ? mu : -1.1f;
            lo = fminf(lo, rmax - 1e-6f);
            const float range = fmaxf(rmax + 1e-6f - lo, 1e-6f);
            sh_lo = lo;
            sh_iw = (float)HB / range;
        }
        for (int i = tid; i < HB; i += CTH) hist[i] = 0u;
        __syncthreads();
        const float lo = sh_lo, iw = sh_iw;
        #pragma unroll
        for (int j = 0; j < NIT; ++j) {
            const int i = tid + j * CTH;
            if (i < NV8) {
                #pragma unroll
                for (int e = 0; e < 8; ++e) {
                    const float v = bf16_up(vals[j][e]);
                    if (v >= lo) {
                        const int bin = min((int)((v - lo) * iw), HB - 1);
                        atomicAdd(&hist[bin], 1u);
                    }
                }
            }
        }
        __syncthreads();
        if (tid == 0) {
            unsigned cum = 0; int t = HB - 1;
            for (; t >= 0; --t) { cum += hist[t]; if (cum >= KMAX) break; }
            if (cum >= KMAX) {
                sh_thr = lo + (float)t / sh_iw - MARGIN;
                sh_done = 1;
            } else sh_done = 0;
        }
        __syncthreads();
        if (sh_done) break;
    }

    // ---- phase 3: compact candidates (from registers) ----
    if (tid == 0) cnt = 0;
    __syncthreads();
    const float ct = sh_thr;
    #pragma unroll
    for (int j = 0; j < NIT; ++j) {
        const int i = tid + j * CTH;
        if (i < NV8) {
            #pragma unroll
            for (int e = 0; e < 8; ++e) {
                if (bf16_up(vals[j][e]) >= ct) {
                    const int p = atomicAdd(&cnt, 1);
                    if (p < MAXC) cidx[p] = i * 8 + e;
                }
            }
        }
    }
    __syncthreads();
    const int m = min(cnt, MAXC);

    // ---- phase 4: fp64 exact re-rank, one candidate per wave (16 waves) ----
    const int wave = tid >> 6, lane = tid & 63;
    const int si = lane >> 3, kg = lane & 7;
    for (int c = wave; c < m; c += 16) {
        const int n = cidx[c];
        const float f = F[(size_t)si * NKEYS + n];
        const float* krow = keys + ((size_t)si * NKEYS + n) * DK + kg * 16;
        const float4 k0 = *reinterpret_cast<const float4*>(krow + 0);
        const float4 k1 = *reinterpret_cast<const float4*>(krow + 4);
        const float4 k2 = *reinterpret_cast<const float4*>(krow + 8);
        const float4 k3 = *reinterpret_cast<const float4*>(krow + 12);
        const float kf[16] = {k0.x, k0.y, k0.z, k0.w, k1.x, k1.y, k1.z, k1.w,
                              k2.x, k2.y, k2.z, k2.w, k3.x, k3.y, k3.z, k3.w};
        double acc = 0.0;
        #pragma unroll
        for (int j = 0; j < 16; ++j) {
            const float q = QT[(size_t)(si * DK + kg * 16 + j) * B_ + b];
            acc += (double)q * ((double)kf[j] * (double)f);
        }
        #pragma unroll
        for (int off = 1; off < 64; off <<= 1) acc += __shfl_xor(acc, off);
        if (lane == 0) cval[c] = acc;
    }
    __syncthreads();

    // ---- phase 5: single-wave exact top-32 (desc value, ties -> asc index) ----
    if (tid < 64) {
        for (int r = 0; r < KMAX; ++r) {
            double bv = -1e300; int bi = 0x7fffffff; int bp = -1;
            for (int c = tid; c < m; c += 64) {
                const double v = cval[c]; const int ix = cidx[c];
                if (v > bv || (v == bv && ix < bi)) { bv = v; bi = ix; bp = c; }
            }
            #pragma unroll
            for (int off = 32; off > 0; off >>= 1) {
                const double ov = __shfl_xor(bv, off);
                const int oi = __shfl_xor(bi, off);
                const int op = __shfl_xor(bp, off);
                if (ov > bv || (ov == bv && oi < bi)) { bv = ov; bi = oi; bp = op; }
            }
            if (tid == 0) { topv[r] = bv; topi[r] = bi; if (bp >= 0) cval[bp] = -1e301; }
        }
        if (tid == 0) {
            const float lamv = lam_p[0];
            const float tauv = tau_p[0];
            const bool warm = warm_p[0] != 0;
            float al[KMAX];
            float ssum = 0.f;
            if (warm) {
                const float x0 = (float)topv[0] / 0.1f;
                for (int i = 0; i < KMAX; ++i) {
                    const float e = expf((float)topv[i] / 0.1f - x0);
                    al[i] = e; ssum += e;
                }
            } else {
                for (int i = 0; i < KMAX; ++i) {
                    const float v = (float)topv[i];
                    const float g = 1.0f / (1.0f + expf(-(lamv * (v - tauv))));
                    const float rr = g * expf(v / 0.1f);
                    al[i] = rr; ssum += rr;
                }
            }
            for (int i = 0; i < KMAX; ++i) {
                out[b * KMAX + i] = al[i] / ssum;
                out[B_ * KMAX + b * KMAX + i] = (float)topi[i];
            }
        }
    }
}

// ---------------------------------------------------------------------------
extern "C" void kernel_launch(void* const* d_in, const int* in_sizes, int n_in,
                              void* d_out, int out_size, void* d_ws, size_t ws_size,
                              hipStream_t stream) {
    const float* z    = (const float*)d_in[0];
    const float* keys = (const float*)d_in[1];
    const float* wq   = (const float*)d_in[2];
    const float* aw   = (const float*)d_in[3];
    const float* tau  = (const float*)d_in[4];
    const float* lam  = (const float*)d_in[5];
    const unsigned char* warm = (const unsigned char*)d_in[6];
    float* out = (float*)d_out;

    char* ws = (char*)d_ws;
    float* QT           = (float*)ws;                          // @0       1.0 MB
    float* F            = (float*)(ws + (1 << 20));            // @1MB     3.2 MB
    __hip_bfloat16* Qb  = (__hip_bfloat16*)(ws + (8 << 20));   // @8MB     0.5 MB
    __hip_bfloat16* Kb  = (__hip_bfloat16*)(ws + (16 << 20));  // @16MB  204.8 MB
    __hip_bfloat16* C   = (__hip_bfloat16*)(ws + ((size_t)232 << 20)); // @232MB 51.2 MB (+slack for OOB-safe Kb reads)

    pass_a_kernel<<<dim3(B_, S_), 128, 0, stream>>>(z, wq, QT, Qb);
    pass_k_kernel<<<dim3((S_ * NKEYS) / 16), 256, 0, stream>>>(keys, aw, F, Kb);
    pass_b_kernel<<<dim3(NBLK), 256, 0, stream>>>(Kb, Qb, C);
    pass_c_kernel<<<dim3(B_), 1024, 0, stream>>>(C, keys, QT, F, tau, lam, warm, out);
}

// Round 5
// 508.159 us; speedup vs baseline: 2.6266x; 1.0588x over previous
//
#include <hip/hip_runtime.h>
#include <hip/hip_bf16.h>
#include <math.h>

#define B_      256
#define DA      1024
#define S_      8
#define DK      128
#define NKEYS   100000
#define KMAX    32
#define KTOT    1024            // S_*DK flattened reduction dim
#define BN      128             // n-tile per block (pass_b)
#define BK      64              // k per LDS step; LDS row = 128 B
#define NBLK    ((NKEYS + BN - 1) / BN)

typedef __attribute__((ext_vector_type(8))) short short8;
typedef __attribute__((ext_vector_type(4))) float f32x4;

typedef const __attribute__((address_space(1))) unsigned gu32;
typedef __attribute__((address_space(3))) unsigned lu32;
#define GLOAD_LDS16(g, s) __builtin_amdgcn_global_load_lds((gu32*)(g), (lu32*)(s), 16, 0, 0)

__device__ __forceinline__ float bf16_up(short h) {
    union { unsigned u; float f; } cv;
    cv.u = ((unsigned)(unsigned short)h) << 16;
    return cv.f;
}

// ---------------------------------------------------------------------------
// Pass A: queries = einsum('ska,ba->bsk', W_Q, z), L2-normalized (fp64 acc).
// (unchanged -- QT must stay bit-identical across rounds)
// ---------------------------------------------------------------------------
__global__ __launch_bounds__(128) void pass_a_kernel(
    const float* __restrict__ z, const float* __restrict__ wq,
    float* __restrict__ QT, __hip_bfloat16* __restrict__ Qb)
{
    const int b = blockIdx.x;
    const int s = blockIdx.y;
    __shared__ float zsh[DA];
    for (int i = threadIdx.x; i < DA; i += 128) zsh[i] = z[b * DA + i];
    __syncthreads();
    const int k = threadIdx.x;
    const float* wrow = wq + (size_t)(s * DK + k) * DA;
    double acc = 0.0;
    #pragma unroll 4
    for (int a = 0; a < DA; a += 4) {
        const float4 w4 = *reinterpret_cast<const float4*>(wrow + a);
        acc += (double)w4.x * (double)zsh[a + 0];
        acc += (double)w4.y * (double)zsh[a + 1];
        acc += (double)w4.z * (double)zsh[a + 2];
        acc += (double)w4.w * (double)zsh[a + 3];
    }
    double sq = acc * acc;
    #pragma unroll
    for (int off = 32; off > 0; off >>= 1) sq += __shfl_down(sq, off);
    __shared__ double part[2];
    if ((threadIdx.x & 63) == 0) part[threadIdx.x >> 6] = sq;
    __syncthreads();
    const double ss  = part[0] + part[1];
    const double inv = 1.0 / (sqrt(ss) + 1e-8);
    const float qv = (float)(acc * inv);
    QT[(size_t)(s * DK + k) * B_ + b] = qv;
    Qb[(size_t)b * KTOT + s * DK + k] = __float2bfloat16(qv);
}

// ---------------------------------------------------------------------------
// Pass K: F + Kb = bf16(key * f). (unchanged from round 4)
// ---------------------------------------------------------------------------
__global__ __launch_bounds__(256) void pass_k_kernel(
    const float* __restrict__ keys, const float* __restrict__ aw,
    float* __restrict__ F, __hip_bfloat16* __restrict__ Kb)
{
    float e[S_];
    float mx = aw[0];
    #pragma unroll
    for (int i = 1; i < S_; ++i) mx = fmaxf(mx, aw[i]);
    float se = 0.f;
    #pragma unroll
    for (int i = 0; i < S_; ++i) { e[i] = expf(aw[i] - mx); se += e[i]; }

    const int g = threadIdx.x >> 4, l = threadIdx.x & 15;
    const long long sn = (long long)blockIdx.x * 16 + g;
    const float* row = keys + (size_t)sn * DK + l * 8;
    const float4 r0 = *reinterpret_cast<const float4*>(row + 0);
    const float4 r1 = *reinterpret_cast<const float4*>(row + 4);
    double sq = (double)r0.x * r0.x + (double)r0.y * r0.y +
                (double)r0.z * r0.z + (double)r0.w * r0.w +
                (double)r1.x * r1.x + (double)r1.y * r1.y +
                (double)r1.z * r1.z + (double)r1.w * r1.w;
    #pragma unroll
    for (int off = 1; off < 16; off <<= 1) sq += __shfl_xor(sq, off);
    const int s = (int)(sn / NKEYS);
    const float w = e[s] / se;
    const float f = (float)((double)w / (sqrt(sq) + 1e-8));
    if (l == 0) F[sn] = f;

    const float vv[8] = {r0.x, r0.y, r0.z, r0.w, r1.x, r1.y, r1.z, r1.w};
    short8 pk;
    #pragma unroll
    for (int ee = 0; ee < 8; ++ee) {
        __hip_bfloat16 h = __float2bfloat16(vv[ee] * f);
        pk[ee] = *reinterpret_cast<short*>(&h);
    }
    *reinterpret_cast<short8*>((__hip_bfloat16*)Kb + (size_t)sn * DK + l * 8) = pk;
}

// ---------------------------------------------------------------------------
// Pass B (restructured): tile 256b x 128n, 512 thr / 8 waves (wave tile 64x64).
// A (Qb) single-buffered 32KB; B (Kb) double-buffered 2x16KB with counted
// s_waitcnt vmcnt(2): B(t+1) loads stay in flight across compute(t) (T3/T4
// minimum pipeline). Raw s_barrier (no full drain). 64KB LDS -> 2 blk/CU.
// Per-output MFMA accumulation order unchanged -> scores bit-identical to R4.
// ---------------------------------------------------------------------------
__global__ __launch_bounds__(512, 4) void pass_b_kernel(
    const __hip_bfloat16* __restrict__ Kb, const __hip_bfloat16* __restrict__ Qb,
    __hip_bfloat16* __restrict__ C)
{
    __shared__ __align__(16) char smem[65536];   // A:[0,32K)  B0:[32K,48K) B1:[48K,64K)
    const int n0 = blockIdx.x * BN;
    const int tid = threadIdx.x;
    const int w = tid >> 6, l = tid & 63;
    const int ln = l & 15, lk = l >> 4;
    const int wm = w >> 1, wn = w & 1;           // 4M x 2N wave grid
    const int sl = l & 7, lr = l >> 3;           // staging slot / row

    f32x4 acc[4][4];
    #pragma unroll
    for (int i = 0; i < 4; ++i)
        #pragma unroll
        for (int j = 0; j < 4; ++j) acc[i][j] = (f32x4){0.f, 0.f, 0.f, 0.f};

    const char* qb = (const char*)Qb;
    const char* kb = (const char*)Kb;

    // ---- B-stage helper (macro-ish lambda): tile index t into buf (t&1) ----
    auto stage_b = [&](int t) {
        const int kc   = t * BK;                 // may be KTOT on last prefetch (slack-guarded)
        const int sidx = kc >> 7;
        const int kl   = kc & (DK - 1);
        #pragma unroll
        for (int i = 0; i < 2; ++i) {
            const int j  = w + 8 * i;            // chunk 0..15
            const int nr = j * 8 + lr;           // tile row 0..127
            const size_t gn = (size_t)sidx * NKEYS + (n0 + nr);
            const char* g = kb + (gn * DK + kl + ((sl ^ (nr & 7)) << 3)) * 2;
            GLOAD_LDS16(g, smem + 32768 + (t & 1) * 16384 + j * 1024);
        }
    };

    // prologue: B(0) in flight
    stage_b(0);

    for (int t = 0; t < 16; ++t) {
        const int kc = t * BK;
        // ---- stage A(t): 32 chunks, 4 per wave, from L2-resident Qb ----
        #pragma unroll
        for (int i = 0; i < 4; ++i) {
            const int j  = w + 8 * i;            // chunk 0..31
            const int bq = j * 8 + lr;           // query row 0..255
            const char* g = qb + ((size_t)bq * KTOT + kc + ((sl ^ (bq & 7)) << 3)) * 2;
            GLOAD_LDS16(g, smem + j * 1024);
        }
        // ---- prefetch B(t+1) into the other buffer ----
        stage_b(t + 1);
        // ---- wait A(t)+B(t) (leave B(t+1)'s 2 issues in flight), barrier ----
        asm volatile("s_waitcnt vmcnt(2)" ::: "memory");
        __builtin_amdgcn_sched_barrier(0);
        __builtin_amdgcn_s_barrier();
        __builtin_amdgcn_sched_barrier(0);
        // ---- compute(t): 16 ds_read_b128 + 32 MFMA per wave ----
        const char* bbase = smem + 32768 + (t & 1) * 16384;
        #pragma unroll
        for (int kw = 0; kw < 2; ++kw) {
            const int slot = kw * 4 + lk;
            short8 af[4], bf[4];
            #pragma unroll
            for (int mi = 0; mi < 4; ++mi) {
                const int bq = wm * 64 + mi * 16 + ln;
                af[mi] = *reinterpret_cast<const short8*>(smem + bq * 128 + ((slot ^ (bq & 7)) << 4));
            }
            #pragma unroll
            for (int nf = 0; nf < 4; ++nf) {
                const int nr = wn * 64 + nf * 16 + ln;
                bf[nf] = *reinterpret_cast<const short8*>(bbase + nr * 128 + ((slot ^ (nr & 7)) << 4));
            }
            #pragma unroll
            for (int mi = 0; mi < 4; ++mi)
                #pragma unroll
                for (int nf = 0; nf < 4; ++nf)
                    acc[mi][nf] = __builtin_amdgcn_mfma_f32_16x16x32_bf16(
                        af[mi], bf[nf], acc[mi][nf], 0, 0, 0);
        }
        // ---- protect A (and B[cur]) from next iteration's staging ----
        __builtin_amdgcn_s_barrier();
    }
    // ---- C store: row=(lane>>4)*4+reg, col=lane&15 (m89-verified layout) ----
    #pragma unroll
    for (int mi = 0; mi < 4; ++mi) {
        #pragma unroll
        for (int nf = 0; nf < 4; ++nf) {
            const int n = n0 + wn * 64 + nf * 16 + ln;
            if (n < NKEYS) {
                #pragma unroll
                for (int r = 0; r < 4; ++r) {
                    const int bq = wm * 64 + mi * 16 + lk * 4 + r;
                    C[(size_t)bq * NKEYS + n] = __float2bfloat16(acc[mi][nf][r]);
                }
            }
        }
    }
}

// ---------------------------------------------------------------------------
// Pass C: unchanged from round 3/4 (exact-rank arithmetic frozen).
// ---------------------------------------------------------------------------
#define MAXC 2048
#define MARGIN 1e-2f
#define HB 1024
#define NV8 12500               // short8's per row (100000/8)
#define CTH 1024                // threads
#define NIT 13                  // ceil(12500/1024)

__global__ __launch_bounds__(1024) void pass_c_kernel(
    const __hip_bfloat16* __restrict__ C, const float* __restrict__ keys,
    const float* __restrict__ QT, const float* __restrict__ F,
    const float* __restrict__ tau_p, const float* __restrict__ lam_p,
    const unsigned char* __restrict__ warm_p, float* __restrict__ out)
{
    const int b = blockIdx.x, tid = threadIdx.x;
    __shared__ float redA[16], redB[16], redC[16];
    __shared__ unsigned hist[HB];
    __shared__ double cval[MAXC];
    __shared__ int cidx[MAXC];
    __shared__ int cnt;
    __shared__ float sh_thr, sh_lo, sh_iw;
    __shared__ int sh_done;
    __shared__ float sh_stat[3];
    __shared__ double topv[KMAX];
    __shared__ int topi[KMAX];

    const __hip_bfloat16* crow = C + (size_t)b * NKEYS;

    // ---- load row once into registers (static indexing; rule #20) ----
    short8 vals[NIT];
    #pragma unroll
    for (int j = 0; j < NIT; ++j) {
        const int i = tid + j * CTH;
        if (i < NV8) vals[j] = *reinterpret_cast<const short8*>(crow + i * 8);
        else { short8 z = {0,0,0,0,0,0,0,0}; vals[j] = z; }
    }

    // ---- phase 1: mean / var / max from registers ----
    float sm = 0.f, sq = 0.f, mx = -2.f;
    #pragma unroll
    for (int j = 0; j < NIT; ++j) {
        const int i = tid + j * CTH;
        if (i < NV8) {
            #pragma unroll
            for (int e = 0; e < 8; ++e) {
                const float v = bf16_up(vals[j][e]);
                sm += v; sq += v * v; mx = fmaxf(mx, v);
            }
        }
    }
    #pragma unroll
    for (int off = 32; off > 0; off >>= 1) {
        sm += __shfl_down(sm, off);
        sq += __shfl_down(sq, off);
        mx = fmaxf(mx, __shfl_down(mx, off));
    }
    if ((tid & 63) == 0) { redA[tid >> 6] = sm; redB[tid >> 6] = sq; redC[tid >> 6] = mx; }
    __syncthreads();
    if (tid == 0) {
        float S1 = 0.f, S2 = 0.f, M = -2.f;
        #pragma unroll
        for (int i = 0; i < 16; ++i) { S1 += redA[i]; S2 += redB[i]; M = fmaxf(M, redC[i]); }
        const float mu = S1 / NKEYS;
        sh_stat[0] = mu;
        sh_stat[1] = sqrtf(fmaxf(S2 / NKEYS - mu * mu, 1e-12f));
        sh_stat[2] = M;
    }
    __syncthreads();
    const float mu = sh_stat[0], sg = sh_stat[1], rmax = sh_stat[2];

    // ---- phase 2: adaptive tail histogram; attempt-loop is airtight ----
    for (int attempt = 0; attempt < 3; ++attempt) {
        if (tid == 0) {
            float lo = (attempt == 0) ? (mu + 2.5f * sg)
                     : (attempt == 1) ? mu : -1.1f;
            lo = fminf(lo, rmax - 1e-6f);
            const float range = fmaxf(rmax + 1e-6f - lo, 1e-6f);
            sh_lo = lo;
            sh_iw = (float)HB / range;
        }
        for (int i = tid; i < HB; i += CTH) hist[i] = 0u;
        __syncthreads();
        const float lo = sh_lo, iw = sh_iw;
        #pragma unroll
        for (int j = 0; j < NIT; ++j) {
            const int i = tid + j * CTH;
            if (i < NV8) {
                #pragma unroll
                for (int e = 0; e < 8; ++e) {
                    const float v = bf16_up(vals[j][e]);
                    if (v >= lo) {
                        const int bin = min((int)((v - lo) * iw), HB - 1);
                        atomicAdd(&hist[bin], 1u);
                    }
                }
            }
        }
        __syncthreads();
        if (tid == 0) {
            unsigned cum = 0; int t = HB - 1;
            for (; t >= 0; --t) { cum += hist[t]; if (cum >= KMAX) break; }
            if (cum >= KMAX) {
                sh_thr = lo + (float)t / sh_iw - MARGIN;
                sh_done = 1;
            } else sh_done = 0;
        }
        __syncthreads();
        if (sh_done) break;
    }

    // ---- phase 3: compact candidates (from registers) ----
    if (tid == 0) cnt = 0;
    __syncthreads();
    const float ct = sh_thr;
    #pragma unroll
    for (int j = 0; j < NIT; ++j) {
        const int i = tid + j * CTH;
        if (i < NV8) {
            #pragma unroll
            for (int e = 0; e < 8; ++e) {
                if (bf16_up(vals[j][e]) >= ct) {
                    const int p = atomicAdd(&cnt, 1);
                    if (p < MAXC) cidx[p] = i * 8 + e;
                }
            }
        }
    }
    __syncthreads();
    const int m = min(cnt, MAXC);

    // ---- phase 4: fp64 exact re-rank, one candidate per wave (16 waves) ----
    const int wave = tid >> 6, lane = tid & 63;
    const int si = lane >> 3, kg = lane & 7;
    for (int c = wave; c < m; c += 16) {
        const int n = cidx[c];
        const float f = F[(size_t)si * NKEYS + n];
        const float* krow = keys + ((size_t)si * NKEYS + n) * DK + kg * 16;
        const float4 k0 = *reinterpret_cast<const float4*>(krow + 0);
        const float4 k1 = *reinterpret_cast<const float4*>(krow + 4);
        const float4 k2 = *reinterpret_cast<const float4*>(krow + 8);
        const float4 k3 = *reinterpret_cast<const float4*>(krow + 12);
        const float kf[16] = {k0.x, k0.y, k0.z, k0.w, k1.x, k1.y, k1.z, k1.w,
                              k2.x, k2.y, k2.z, k2.w, k3.x, k3.y, k3.z, k3.w};
        double acc = 0.0;
        #pragma unroll
        for (int j = 0; j < 16; ++j) {
            const float q = QT[(size_t)(si * DK + kg * 16 + j) * B_ + b];
            acc += (double)q * ((double)kf[j] * (double)f);
        }
        #pragma unroll
        for (int off = 1; off < 64; off <<= 1) acc += __shfl_xor(acc, off);
        if (lane == 0) cval[c] = acc;
    }
    __syncthreads();

    // ---- phase 5: single-wave exact top-32 (desc value, ties -> asc index) ----
    if (tid < 64) {
        for (int r = 0; r < KMAX; ++r) {
            double bv = -1e300; int bi = 0x7fffffff; int bp = -1;
            for (int c = tid; c < m; c += 64) {
                const double v = cval[c]; const int ix = cidx[c];
                if (v > bv || (v == bv && ix < bi)) { bv = v; bi = ix; bp = c; }
            }
            #pragma unroll
            for (int off = 32; off > 0; off >>= 1) {
                const double ov = __shfl_xor(bv, off);
                const int oi = __shfl_xor(bi, off);
                const int op = __shfl_xor(bp, off);
                if (ov > bv || (ov == bv && oi < bi)) { bv = ov; bi = oi; bp = op; }
            }
            if (tid == 0) { topv[r] = bv; topi[r] = bi; if (bp >= 0) cval[bp] = -1e301; }
        }
        if (tid == 0) {
            const float lamv = lam_p[0];
            const float tauv = tau_p[0];
            const bool warm = warm_p[0] != 0;
            float al[KMAX];
            float ssum = 0.f;
            if (warm) {
                const float x0 = (float)topv[0] / 0.1f;
                for (int i = 0; i < KMAX; ++i) {
                    const float e = expf((float)topv[i] / 0.1f - x0);
                    al[i] = e; ssum += e;
                }
            } else {
                for (int i = 0; i < KMAX; ++i) {
                    const float v = (float)topv[i];
                    const float g = 1.0f / (1.0f + expf(-(lamv * (v - tauv))));
                    const float rr = g * expf(v / 0.1f);
                    al[i] = rr; ssum += rr;
                }
            }
            for (int i = 0; i < KMAX; ++i) {
                out[b * KMAX + i] = al[i] / ssum;
                out[B_ * KMAX + b * KMAX + i] = (float)topi[i];
            }
        }
    }
}

// ---------------------------------------------------------------------------
extern "C" void kernel_launch(void* const* d_in, const int* in_sizes, int n_in,
                              void* d_out, int out_size, void* d_ws, size_t ws_size,
                              hipStream_t stream) {
    const float* z    = (const float*)d_in[0];
    const float* keys = (const float*)d_in[1];
    const float* wq   = (const float*)d_in[2];
    const float* aw   = (const float*)d_in[3];
    const float* tau  = (const float*)d_in[4];
    const float* lam  = (const float*)d_in[5];
    const unsigned char* warm = (const unsigned char*)d_in[6];
    float* out = (float*)d_out;

    char* ws = (char*)d_ws;
    float* QT           = (float*)ws;                          // @0       1.0 MB
    float* F            = (float*)(ws + (1 << 20));            // @1MB     3.2 MB
    __hip_bfloat16* Qb  = (__hip_bfloat16*)(ws + (8 << 20));   // @8MB     0.5 MB
    __hip_bfloat16* Kb  = (__hip_bfloat16*)(ws + (16 << 20));  // @16MB  204.8 MB
    __hip_bfloat16* C   = (__hip_bfloat16*)(ws + ((size_t)232 << 20)); // @232MB 51.2 MB (slack before C absorbs OOB/prefetch Kb reads)

    pass_a_kernel<<<dim3(B_, S_), 128, 0, stream>>>(z, wq, QT, Qb);
    pass_k_kernel<<<dim3((S_ * NKEYS) / 16), 256, 0, stream>>>(keys, aw, F, Kb);
    pass_b_kernel<<<dim3(NBLK), 512, 0, stream>>>(Kb, Qb, C);
    pass_c_kernel<<<dim3(B_), 1024, 0, stream>>>(C, keys, QT, F, tau, lam, warm, out);
}

// Round 6
// 452.233 us; speedup vs baseline: 2.9514x; 1.1237x over previous
//
#include <hip/hip_runtime.h>
#include <hip/hip_bf16.h>
#include <math.h>

#define B_      256
#define DA      1024
#define S_      8
#define DK      128
#define NKEYS   100000
#define KMAX    32
#define KTOT    1024            // S_*DK flattened reduction dim
#define BN      128             // n-tile per block (pass_b)
#define BK      64              // k per LDS step; LDS row = 128 B
#define NBLK    ((NKEYS + BN - 1) / BN)

typedef __attribute__((ext_vector_type(8))) short short8;
typedef __attribute__((ext_vector_type(4))) float f32x4;

typedef const __attribute__((address_space(1))) unsigned gu32;
typedef __attribute__((address_space(3))) unsigned lu32;
#define GLOAD_LDS16(g, s) __builtin_amdgcn_global_load_lds((gu32*)(g), (lu32*)(s), 16, 0, 0)

__device__ __forceinline__ float bf16_up(short h) {
    union { unsigned u; float f; } cv;
    cv.u = ((unsigned)(unsigned short)h) << 16;
    return cv.f;
}

// ---------------------------------------------------------------------------
// Pass A: queries = einsum('ska,ba->bsk', W_Q, z), L2-normalized (fp64 acc).
// (unchanged -- QT must stay bit-identical across rounds)
// ---------------------------------------------------------------------------
__global__ __launch_bounds__(128) void pass_a_kernel(
    const float* __restrict__ z, const float* __restrict__ wq,
    float* __restrict__ QT, __hip_bfloat16* __restrict__ Qb)
{
    const int b = blockIdx.x;
    const int s = blockIdx.y;
    __shared__ float zsh[DA];
    for (int i = threadIdx.x; i < DA; i += 128) zsh[i] = z[b * DA + i];
    __syncthreads();
    const int k = threadIdx.x;
    const float* wrow = wq + (size_t)(s * DK + k) * DA;
    double acc = 0.0;
    #pragma unroll 4
    for (int a = 0; a < DA; a += 4) {
        const float4 w4 = *reinterpret_cast<const float4*>(wrow + a);
        acc += (double)w4.x * (double)zsh[a + 0];
        acc += (double)w4.y * (double)zsh[a + 1];
        acc += (double)w4.z * (double)zsh[a + 2];
        acc += (double)w4.w * (double)zsh[a + 3];
    }
    double sq = acc * acc;
    #pragma unroll
    for (int off = 32; off > 0; off >>= 1) sq += __shfl_down(sq, off);
    __shared__ double part[2];
    if ((threadIdx.x & 63) == 0) part[threadIdx.x >> 6] = sq;
    __syncthreads();
    const double ss  = part[0] + part[1];
    const double inv = 1.0 / (sqrt(ss) + 1e-8);
    const float qv = (float)(acc * inv);
    QT[(size_t)(s * DK + k) * B_ + b] = qv;
    Qb[(size_t)b * KTOT + s * DK + k] = __float2bfloat16(qv);
}

// ---------------------------------------------------------------------------
// Pass K: F + Kb = bf16(key * f). (unchanged from round 4)
// ---------------------------------------------------------------------------
__global__ __launch_bounds__(256) void pass_k_kernel(
    const float* __restrict__ keys, const float* __restrict__ aw,
    float* __restrict__ F, __hip_bfloat16* __restrict__ Kb)
{
    float e[S_];
    float mx = aw[0];
    #pragma unroll
    for (int i = 1; i < S_; ++i) mx = fmaxf(mx, aw[i]);
    float se = 0.f;
    #pragma unroll
    for (int i = 0; i < S_; ++i) { e[i] = expf(aw[i] - mx); se += e[i]; }

    const int g = threadIdx.x >> 4, l = threadIdx.x & 15;
    const long long sn = (long long)blockIdx.x * 16 + g;
    const float* row = keys + (size_t)sn * DK + l * 8;
    const float4 r0 = *reinterpret_cast<const float4*>(row + 0);
    const float4 r1 = *reinterpret_cast<const float4*>(row + 4);
    double sq = (double)r0.x * r0.x + (double)r0.y * r0.y +
                (double)r0.z * r0.z + (double)r0.w * r0.w +
                (double)r1.x * r1.x + (double)r1.y * r1.y +
                (double)r1.z * r1.z + (double)r1.w * r1.w;
    #pragma unroll
    for (int off = 1; off < 16; off <<= 1) sq += __shfl_xor(sq, off);
    const int s = (int)(sn / NKEYS);
    const float w = e[s] / se;
    const float f = (float)((double)w / (sqrt(sq) + 1e-8));
    if (l == 0) F[sn] = f;

    const float vv[8] = {r0.x, r0.y, r0.z, r0.w, r1.x, r1.y, r1.z, r1.w};
    short8 pk;
    #pragma unroll
    for (int ee = 0; ee < 8; ++ee) {
        __hip_bfloat16 h = __float2bfloat16(vv[ee] * f);
        pk[ee] = *reinterpret_cast<short*>(&h);
    }
    *reinterpret_cast<short8*>((__hip_bfloat16*)Kb + (size_t)sn * DK + l * 8) = pk;
}

// ---------------------------------------------------------------------------
// Pass B: unchanged from round 5 (scores bit-identical).
// ---------------------------------------------------------------------------
__global__ __launch_bounds__(512, 4) void pass_b_kernel(
    const __hip_bfloat16* __restrict__ Kb, const __hip_bfloat16* __restrict__ Qb,
    __hip_bfloat16* __restrict__ C)
{
    __shared__ __align__(16) char smem[65536];   // A:[0,32K)  B0:[32K,48K) B1:[48K,64K)
    const int n0 = blockIdx.x * BN;
    const int tid = threadIdx.x;
    const int w = tid >> 6, l = tid & 63;
    const int ln = l & 15, lk = l >> 4;
    const int wm = w >> 1, wn = w & 1;           // 4M x 2N wave grid
    const int sl = l & 7, lr = l >> 3;           // staging slot / row

    f32x4 acc[4][4];
    #pragma unroll
    for (int i = 0; i < 4; ++i)
        #pragma unroll
        for (int j = 0; j < 4; ++j) acc[i][j] = (f32x4){0.f, 0.f, 0.f, 0.f};

    const char* qb = (const char*)Qb;
    const char* kb = (const char*)Kb;

    auto stage_b = [&](int t) {
        const int kc   = t * BK;                 // may be KTOT on last prefetch (slack-guarded)
        const int sidx = kc >> 7;
        const int kl   = kc & (DK - 1);
        #pragma unroll
        for (int i = 0; i < 2; ++i) {
            const int j  = w + 8 * i;            // chunk 0..15
            const int nr = j * 8 + lr;           // tile row 0..127
            const size_t gn = (size_t)sidx * NKEYS + (n0 + nr);
            const char* g = kb + (gn * DK + kl + ((sl ^ (nr & 7)) << 3)) * 2;
            GLOAD_LDS16(g, smem + 32768 + (t & 1) * 16384 + j * 1024);
        }
    };

    stage_b(0);

    for (int t = 0; t < 16; ++t) {
        const int kc = t * BK;
        #pragma unroll
        for (int i = 0; i < 4; ++i) {
            const int j  = w + 8 * i;            // chunk 0..31
            const int bq = j * 8 + lr;           // query row 0..255
            const char* g = qb + ((size_t)bq * KTOT + kc + ((sl ^ (bq & 7)) << 3)) * 2;
            GLOAD_LDS16(g, smem + j * 1024);
        }
        stage_b(t + 1);
        asm volatile("s_waitcnt vmcnt(2)" ::: "memory");
        __builtin_amdgcn_sched_barrier(0);
        __builtin_amdgcn_s_barrier();
        __builtin_amdgcn_sched_barrier(0);
        const char* bbase = smem + 32768 + (t & 1) * 16384;
        #pragma unroll
        for (int kw = 0; kw < 2; ++kw) {
            const int slot = kw * 4 + lk;
            short8 af[4], bf[4];
            #pragma unroll
            for (int mi = 0; mi < 4; ++mi) {
                const int bq = wm * 64 + mi * 16 + ln;
                af[mi] = *reinterpret_cast<const short8*>(smem + bq * 128 + ((slot ^ (bq & 7)) << 4));
            }
            #pragma unroll
            for (int nf = 0; nf < 4; ++nf) {
                const int nr = wn * 64 + nf * 16 + ln;
                bf[nf] = *reinterpret_cast<const short8*>(bbase + nr * 128 + ((slot ^ (nr & 7)) << 4));
            }
            #pragma unroll
            for (int mi = 0; mi < 4; ++mi)
                #pragma unroll
                for (int nf = 0; nf < 4; ++nf)
                    acc[mi][nf] = __builtin_amdgcn_mfma_f32_16x16x32_bf16(
                        af[mi], bf[nf], acc[mi][nf], 0, 0, 0);
        }
        __builtin_amdgcn_s_barrier();
    }
    #pragma unroll
    for (int mi = 0; mi < 4; ++mi) {
        #pragma unroll
        for (int nf = 0; nf < 4; ++nf) {
            const int n = n0 + wn * 64 + nf * 16 + ln;
            if (n < NKEYS) {
                #pragma unroll
                for (int r = 0; r < 4; ++r) {
                    const int bq = wm * 64 + mi * 16 + lk * 4 + r;
                    C[(size_t)bq * NKEYS + n] = __float2bfloat16(acc[mi][nf][r]);
                }
            }
        }
    }
}

// ---------------------------------------------------------------------------
// Pass C (de-spilled): STREAM the row from cache each phase instead of
// caching it in 52 VGPRs (R3-R5 register residency spanned all phases ->
// spill at 1024 thr). C is L2/L3-resident (51.2 MB, freshly written);
// re-streaming is ~free. Thresholds + fp64 re-rank + top-32 identical ->
// output bit-identical to R5.
// ---------------------------------------------------------------------------
#define MAXC 2048
#define MARGIN 1e-2f
#define HB 1024
#define NV8 12500               // short8's per row (100000/8)
#define CTH 1024                // threads

__global__ __launch_bounds__(1024) void pass_c_kernel(
    const __hip_bfloat16* __restrict__ C, const float* __restrict__ keys,
    const float* __restrict__ QT, const float* __restrict__ F,
    const float* __restrict__ tau_p, const float* __restrict__ lam_p,
    const unsigned char* __restrict__ warm_p, float* __restrict__ out)
{
    const int b = blockIdx.x, tid = threadIdx.x;
    __shared__ float redA[16], redB[16], redC[16];
    __shared__ unsigned hist[HB];
    __shared__ double cval[MAXC];
    __shared__ int cidx[MAXC];
    __shared__ int cnt;
    __shared__ float sh_thr, sh_lo, sh_iw;
    __shared__ int sh_done;
    __shared__ float sh_stat[3];
    __shared__ double topv[KMAX];
    __shared__ int topi[KMAX];

    const __hip_bfloat16* crow = C + (size_t)b * NKEYS;

    // ---- phase 1: mean / var / max (streaming short8) ----
    float sm = 0.f, sq = 0.f, mx = -2.f;
    for (int i = tid; i < NV8; i += CTH) {
        const short8 v8 = *reinterpret_cast<const short8*>(crow + i * 8);
        #pragma unroll
        for (int e = 0; e < 8; ++e) {
            const float v = bf16_up(v8[e]);
            sm += v; sq += v * v; mx = fmaxf(mx, v);
        }
    }
    #pragma unroll
    for (int off = 32; off > 0; off >>= 1) {
        sm += __shfl_down(sm, off);
        sq += __shfl_down(sq, off);
        mx = fmaxf(mx, __shfl_down(mx, off));
    }
    if ((tid & 63) == 0) { redA[tid >> 6] = sm; redB[tid >> 6] = sq; redC[tid >> 6] = mx; }
    __syncthreads();
    if (tid == 0) {
        float S1 = 0.f, S2 = 0.f, M = -2.f;
        #pragma unroll
        for (int i = 0; i < 16; ++i) { S1 += redA[i]; S2 += redB[i]; M = fmaxf(M, redC[i]); }
        const float mu = S1 / NKEYS;
        sh_stat[0] = mu;
        sh_stat[1] = sqrtf(fmaxf(S2 / NKEYS - mu * mu, 1e-12f));
        sh_stat[2] = M;
    }
    __syncthreads();
    const float mu = sh_stat[0], sg = sh_stat[1], rmax = sh_stat[2];

    // ---- phase 2: adaptive tail histogram (streaming); attempt loop airtight ----
    for (int attempt = 0; attempt < 3; ++attempt) {
        if (tid == 0) {
            float lo = (attempt == 0) ? (mu + 2.5f * sg)
                     : (attempt == 1) ? mu : -1.1f;
            lo = fminf(lo, rmax - 1e-6f);
            const float range = fmaxf(rmax + 1e-6f - lo, 1e-6f);
            sh_lo = lo;
            sh_iw = (float)HB / range;
        }
        for (int i = tid; i < HB; i += CTH) hist[i] = 0u;
        __syncthreads();
        const float lo = sh_lo, iw = sh_iw;
        for (int i = tid; i < NV8; i += CTH) {
            const short8 v8 = *reinterpret_cast<const short8*>(crow + i * 8);
            #pragma unroll
            for (int e = 0; e < 8; ++e) {
                const float v = bf16_up(v8[e]);
                if (v >= lo) {
                    const int bin = min((int)((v - lo) * iw), HB - 1);
                    atomicAdd(&hist[bin], 1u);
                }
            }
        }
        __syncthreads();
        if (tid == 0) {
            unsigned cum = 0; int t = HB - 1;
            for (; t >= 0; --t) { cum += hist[t]; if (cum >= KMAX) break; }
            if (cum >= KMAX) {
                sh_thr = lo + (float)t / sh_iw - MARGIN;
                sh_done = 1;
            } else sh_done = 0;
        }
        __syncthreads();
        if (sh_done) break;
    }

    // ---- phase 3: compact candidates (streaming) ----
    if (tid == 0) cnt = 0;
    __syncthreads();
    const float ct = sh_thr;
    for (int i = tid; i < NV8; i += CTH) {
        const short8 v8 = *reinterpret_cast<const short8*>(crow + i * 8);
        #pragma unroll
        for (int e = 0; e < 8; ++e) {
            if (bf16_up(v8[e]) >= ct) {
                const int p = atomicAdd(&cnt, 1);
                if (p < MAXC) cidx[p] = i * 8 + e;
            }
        }
    }
    __syncthreads();
    const int m = min(cnt, MAXC);

    // ---- phase 4: fp64 exact re-rank, one candidate per wave (16 waves) ----
    const int wave = tid >> 6, lane = tid & 63;
    const int si = lane >> 3, kg = lane & 7;
    for (int c = wave; c < m; c += 16) {
        const int n = cidx[c];
        const float f = F[(size_t)si * NKEYS + n];
        const float* krow = keys + ((size_t)si * NKEYS + n) * DK + kg * 16;
        const float4 k0 = *reinterpret_cast<const float4*>(krow + 0);
        const float4 k1 = *reinterpret_cast<const float4*>(krow + 4);
        const float4 k2 = *reinterpret_cast<const float4*>(krow + 8);
        const float4 k3 = *reinterpret_cast<const float4*>(krow + 12);
        const float kf[16] = {k0.x, k0.y, k0.z, k0.w, k1.x, k1.y, k1.z, k1.w,
                              k2.x, k2.y, k2.z, k2.w, k3.x, k3.y, k3.z, k3.w};
        double acc = 0.0;
        #pragma unroll
        for (int j = 0; j < 16; ++j) {
            const float q = QT[(size_t)(si * DK + kg * 16 + j) * B_ + b];
            acc += (double)q * ((double)kf[j] * (double)f);
        }
        #pragma unroll
        for (int off = 1; off < 64; off <<= 1) acc += __shfl_xor(acc, off);
        if (lane == 0) cval[c] = acc;
    }
    __syncthreads();

    // ---- phase 5: single-wave exact top-32 (desc value, ties -> asc index) ----
    if (tid < 64) {
        for (int r = 0; r < KMAX; ++r) {
            double bv = -1e300; int bi = 0x7fffffff; int bp = -1;
            for (int c = tid; c < m; c += 64) {
                const double v = cval[c]; const int ix = cidx[c];
                if (v > bv || (v == bv && ix < bi)) { bv = v; bi = ix; bp = c; }
            }
            #pragma unroll
            for (int off = 32; off > 0; off >>= 1) {
                const double ov = __shfl_xor(bv, off);
                const int oi = __shfl_xor(bi, off);
                const int op = __shfl_xor(bp, off);
                if (ov > bv || (ov == bv && oi < bi)) { bv = ov; bi = oi; bp = op; }
            }
            if (tid == 0) { topv[r] = bv; topi[r] = bi; if (bp >= 0) cval[bp] = -1e301; }
        }
        if (tid == 0) {
            const float lamv = lam_p[0];
            const float tauv = tau_p[0];
            const bool warm = warm_p[0] != 0;
            float al[KMAX];
            float ssum = 0.f;
            if (warm) {
                const float x0 = (float)topv[0] / 0.1f;
                for (int i = 0; i < KMAX; ++i) {
                    const float e = expf((float)topv[i] / 0.1f - x0);
                    al[i] = e; ssum += e;
                }
            } else {
                for (int i = 0; i < KMAX; ++i) {
                    const float v = (float)topv[i];
                    const float g = 1.0f / (1.0f + expf(-(lamv * (v - tauv))));
                    const float rr = g * expf(v / 0.1f);
                    al[i] = rr; ssum += rr;
                }
            }
            for (int i = 0; i < KMAX; ++i) {
                out[b * KMAX + i] = al[i] / ssum;
                out[B_ * KMAX + b * KMAX + i] = (float)topi[i];
            }
        }
    }
}

// ---------------------------------------------------------------------------
extern "C" void kernel_launch(void* const* d_in, const int* in_sizes, int n_in,
                              void* d_out, int out_size, void* d_ws, size_t ws_size,
                              hipStream_t stream) {
    const float* z    = (const float*)d_in[0];
    const float* keys = (const float*)d_in[1];
    const float* wq   = (const float*)d_in[2];
    const float* aw   = (const float*)d_in[3];
    const float* tau  = (const float*)d_in[4];
    const float* lam  = (const float*)d_in[5];
    const unsigned char* warm = (const unsigned char*)d_in[6];
    float* out = (float*)d_out;

    char* ws = (char*)d_ws;
    float* QT           = (float*)ws;                          // @0       1.0 MB
    float* F            = (float*)(ws + (1 << 20));            // @1MB     3.2 MB
    __hip_bfloat16* Qb  = (__hip_bfloat16*)(ws + (8 << 20));   // @8MB     0.5 MB
    __hip_bfloat16* Kb  = (__hip_bfloat16*)(ws + (16 << 20));  // @16MB  204.8 MB
    __hip_bfloat16* C   = (__hip_bfloat16*)(ws + ((size_t)232 << 20)); // @232MB 51.2 MB (slack before C absorbs OOB/prefetch Kb reads)

    pass_a_kernel<<<dim3(B_, S_), 128, 0, stream>>>(z, wq, QT, Qb);
    pass_k_kernel<<<dim3((S_ * NKEYS) / 16), 256, 0, stream>>>(keys, aw, F, Kb);
    pass_b_kernel<<<dim3(NBLK), 512, 0, stream>>>(Kb, Qb, C);
    pass_c_kernel<<<dim3(B_), 1024, 0, stream>>>(C, keys, QT, F, tau, lam, warm, out);
}